// Round 15
// baseline (572.674 us; speedup 1.0000x reference)
//
#include <hip/hip_runtime.h>
#include <hip/hip_bf16.h>
#include <cstddef>
#include <cstdint>

static inline int cdiv(int a, int b) { return (a + b - 1) / b; }

typedef short short8v __attribute__((ext_vector_type(8)));
typedef float float4v __attribute__((ext_vector_type(4)));

__device__ inline unsigned short f2b(float f) {
    union { float f; unsigned u; } x; x.f = f;
    unsigned u = x.u;
    return (unsigned short)((u + 0x7fff + ((u >> 16) & 1)) >> 16);
}

__device__ inline float lo2f(unsigned u) { union { unsigned x; float f; } c; c.x = u << 16; return c.f; }
__device__ inline float hi2f(unsigned u) { union { unsigned x; float f; } c; c.x = u & 0xffff0000u; return c.f; }
__device__ inline float b2f(unsigned short b) {
    union { unsigned u; float f; } x; x.u = ((unsigned)b) << 16;
    return x.f;
}

__device__ __forceinline__ void u4tof8(uint4 u, float* f) {
    f[0] = lo2f(u.x); f[1] = hi2f(u.x); f[2] = lo2f(u.y); f[3] = hi2f(u.y);
    f[4] = lo2f(u.z); f[5] = hi2f(u.z); f[6] = lo2f(u.w); f[7] = hi2f(u.w);
}

// async global -> LDS, 16 bytes per lane (wave-uniform LDS base + lane*16)
__device__ __forceinline__ void gload_lds16(const unsigned short* g, unsigned short* lds) {
    __builtin_amdgcn_global_load_lds(
        (const __attribute__((address_space(1))) unsigned int*)g,
        (__attribute__((address_space(3))) unsigned int*)lds, 16, 0, 0);
}

// ---------------- CSR build ----------------

__global__ void count_kernel(const int* __restrict__ ei, int* __restrict__ indeg, int E) {
    int e = blockIdx.x * blockDim.x + threadIdx.x;
    if (e < E) atomicAdd(&indeg[ei[E + e]], 1);
}

__global__ void scan1_kernel(const int* __restrict__ deg, int* __restrict__ offs,
                             int* __restrict__ bsum, int n) {
    __shared__ int tmp[256];
    int i = blockIdx.x * 256 + threadIdx.x;
    int v = (i < n) ? deg[i] : 0;
    tmp[threadIdx.x] = v;
    __syncthreads();
    for (int d = 1; d < 256; d <<= 1) {
        int a = (threadIdx.x >= (unsigned)d) ? tmp[threadIdx.x - d] : 0;
        __syncthreads();
        tmp[threadIdx.x] += a;
        __syncthreads();
    }
    if (i < n) offs[i + 1] = tmp[threadIdx.x];
    if (threadIdx.x == 255) bsum[blockIdx.x] = tmp[255];
}

__global__ void scan2_kernel(int* __restrict__ bsum, int* __restrict__ offs, int nb) {
    if (threadIdx.x == 0) {
        offs[0] = 0;
        int base = 0;
        for (int b = 0; b < nb; ++b) { int t = bsum[b]; bsum[b] = base; base += t; }
    }
}

__global__ void scan3_kernel(int* __restrict__ offs, const int* __restrict__ bsum, int n) {
    int i = blockIdx.x * 256 + threadIdx.x;
    if (i < n) offs[i + 1] += bsum[blockIdx.x];
}

__global__ void fill_kernel(const int* __restrict__ ei, const int* __restrict__ offs,
                            int* __restrict__ cursor, int* __restrict__ csrc, int E) {
    int e = blockIdx.x * blockDim.x + threadIdx.x;
    if (e < E) {
        int d = ei[E + e];
        int s = ei[e];
        int pos = atomicAdd(&cursor[d], 1);
        csrc[offs[d] + pos] = s;
    }
}

// ---------------- fp32 -> bf16 ----------------

__global__ void f2b_kernel(const float* __restrict__ in, unsigned short* __restrict__ out, int n4) {
    int stride = gridDim.x * blockDim.x;
    for (int i = blockIdx.x * blockDim.x + threadIdx.x; i < n4; i += stride) {
        float4 v = reinterpret_cast<const float4*>(in)[i];
        ushort4 o;
        o.x = f2b(v.x); o.y = f2b(v.y); o.z = f2b(v.z); o.w = f2b(v.w);
        reinterpret_cast<ushort4*>(out)[i] = o;
    }
}

// Transpose+convert 16 big weights [512][512] fp32 -> bf16 [Nc][K].
__global__ void transpose_b16_kernel(const float* __restrict__ Wq, const float* __restrict__ Wk,
                                     const float* __restrict__ Wv, const float* __restrict__ Ws,
                                     unsigned short* __restrict__ out) {
    const int K = 512, Nc = 512;
    int z = blockIdx.z;
    int which = z & 3;
    const float* W = (which == 0) ? Wq : (which == 1) ? Wk : (which == 2) ? Wv : Ws;
    W += (size_t)(z >> 2) * K * Nc;
    unsigned short* Wt = out + (size_t)z * K * Nc;
    __shared__ float t[32][33];
    int k0 = blockIdx.x * 32, c0 = blockIdx.y * 32;
    int tx = threadIdx.x, ty = threadIdx.y;
    #pragma unroll
    for (int i = 0; i < 32; i += 8) t[ty + i][tx] = W[(size_t)(k0 + ty + i) * Nc + c0 + tx];
    __syncthreads();
    #pragma unroll
    for (int i = 0; i < 32; i += 8) Wt[(size_t)(c0 + ty + i) * K + k0 + tx] = f2b(t[tx][ty + i]);
}

// Batched transpose of 9 small weights.
struct SmallT {
    const float* src[9];
    unsigned short* dst[9];
    int rows[9];
    int cols[9];
};

__global__ void transpose_small_kernel(SmallT p) {
    int mat = blockIdx.y;
    int rows = p.rows[mat], cols = p.cols[mat];
    int tilesC = cols >> 5;
    int tiles = (rows >> 5) * tilesC;
    if ((int)blockIdx.x >= tiles) return;
    int tr = blockIdx.x / tilesC, tc = blockIdx.x % tilesC;
    const float* src = p.src[mat];
    unsigned short* dst = p.dst[mat];
    __shared__ float t[32][33];
    int r0 = tr * 32, c0 = tc * 32;
    int tx = threadIdx.x, ty = threadIdx.y;
    #pragma unroll
    for (int i = 0; i < 32; i += 8) t[ty + i][tx] = src[(size_t)(r0 + ty + i) * cols + c0 + tx];
    __syncthreads();
    #pragma unroll
    for (int i = 0; i < 32; i += 8) dst[(size_t)(c0 + ty + i) * rows + r0 + tx] = f2b(t[tx][ty + i]);
}

// ---------------- fused bf16 MFMA GEMM (512x512), 3-deep counted-vmcnt pipeline ----------------

struct GemmPtrs {
    const unsigned short* B[4];
    const float* bias[4];
    void* C[4];
    int bf16[4];
};

__global__ __launch_bounds__(256) void mfma_gemm4(const unsigned short* __restrict__ A,
                                                  GemmPtrs p, int M, int nb) {
    __shared__ unsigned short As[3][128 * 32];
    __shared__ unsigned short Bs[3][128 * 32];
    int i = blockIdx.x;
    int wk = (nb & 7) ? i : ((i & 7) * (nb >> 3) + (i >> 3));  // T1 XCD swizzle
    int xt = wk >> 4, yt = wk & 15;
    int row0 = xt * 128;
    int wsel = yt >> 2;
    int col0 = (yt & 3) * 128;
    const unsigned short* Bt = p.B[wsel];

    int tid = threadIdx.x;
    int lane = tid & 63;
    int w = tid >> 6;
    int wr = w >> 1, wc = w & 1;
    float4v acc[4][4] = {};

    int c0i = w * 2;
    int srow0 = c0i * 16 + (lane >> 2);
    int srow1 = srow0 + 16;
    int sslot0 = (lane & 3) ^ ((srow0 >> 1) & 3);   // T2 pre-swizzled 16B slot
    int sslot1 = (lane & 3) ^ ((srow1 >> 1) & 3);

    const unsigned short* Ag0 = A + (size_t)(row0 + srow0) * 512 + sslot0 * 8;
    const unsigned short* Ag1 = A + (size_t)(row0 + srow1) * 512 + sslot1 * 8;
    const unsigned short* Bg0 = Bt + (size_t)(col0 + srow0) * 512 + sslot0 * 8;
    const unsigned short* Bg1 = Bt + (size_t)(col0 + srow1) * 512 + sslot1 * 8;

    #pragma unroll
    for (int t = 0; t < 3; ++t) {
        gload_lds16(Ag0 + t * 32, &As[t][c0i * 512]);
        gload_lds16(Ag1 + t * 32, &As[t][(c0i + 1) * 512]);
        gload_lds16(Bg0 + t * 32, &Bs[t][c0i * 512]);
        gload_lds16(Bg1 + t * 32, &Bs[t][(c0i + 1) * 512]);
    }

    int r16 = lane & 15;
    int ks = lane >> 4;

    #pragma unroll
    for (int kt = 0; kt < 16; ++kt) {
        if (kt <= 13)      { asm volatile("s_waitcnt vmcnt(8)" ::: "memory"); }
        else if (kt == 14) { asm volatile("s_waitcnt vmcnt(4)" ::: "memory"); }
        else               { asm volatile("s_waitcnt vmcnt(0)" ::: "memory"); }
        __builtin_amdgcn_sched_barrier(0);
        __builtin_amdgcn_s_barrier();
        int buf = kt % 3;
        short8v af[4], bf[4];
        #pragma unroll
        for (int mi = 0; mi < 4; ++mi) {
            int row = wr * 64 + mi * 16 + r16;
            int slot = ks ^ ((row >> 1) & 3);
            af[mi] = *reinterpret_cast<const short8v*>(&As[buf][row * 32 + slot * 8]);
        }
        #pragma unroll
        for (int nj = 0; nj < 4; ++nj) {
            int row = wc * 64 + nj * 16 + r16;
            int slot = ks ^ ((row >> 1) & 3);
            bf[nj] = *reinterpret_cast<const short8v*>(&Bs[buf][row * 32 + slot * 8]);
        }
        #pragma unroll
        for (int mi = 0; mi < 4; ++mi)
            #pragma unroll
            for (int nj = 0; nj < 4; ++nj)
                acc[mi][nj] = __builtin_amdgcn_mfma_f32_16x16x32_bf16(af[mi], bf[nj], acc[mi][nj], 0, 0, 0);
        __builtin_amdgcn_s_barrier();
        if (kt <= 12) {
            int nk = (kt + 3) * 32;
            gload_lds16(Ag0 + nk, &As[buf][c0i * 512]);
            gload_lds16(Ag1 + nk, &As[buf][(c0i + 1) * 512]);
            gload_lds16(Bg0 + nk, &Bs[buf][c0i * 512]);
            gload_lds16(Bg1 + nk, &Bs[buf][(c0i + 1) * 512]);
        }
    }

    const float* bias = p.bias[wsel];
    int outbf = p.bf16[wsel];
    float* Cf = (float*)p.C[wsel];
    unsigned short* Cb = (unsigned short*)p.C[wsel];
    int crow_base = row0 + wr * 64 + (lane >> 4) * 4;
    int ccol_base = col0 + wc * 64 + (lane & 15);
    #pragma unroll
    for (int mi = 0; mi < 4; ++mi) {
        #pragma unroll
        for (int r = 0; r < 4; ++r) {
            int grow = crow_base + mi * 16 + r;
            if (grow >= M) continue;
            #pragma unroll
            for (int nj = 0; nj < 4; ++nj) {
                int gcol = ccol_base + nj * 16;
                float val = acc[mi][nj][r] + bias[gcol];
                if (outbf) Cb[(size_t)grow * 512 + gcol] = f2b(val);
                else       Cf[(size_t)grow * 512 + gcol] = val;
            }
        }
    }
}

// ---------------- flexible MFMA GEMM: BM=128, BN=64, BK=32, runtime K/N ----------------

__global__ __launch_bounds__(256) void mfma_flex(const unsigned short* __restrict__ A,
                                                 GemmPtrs p, int M, int K, int Nc) {
    __shared__ unsigned short As[128][40];
    __shared__ unsigned short Bs[64][40];
    int tid = threadIdx.x;
    int lane = tid & 63;
    int w = tid >> 6;
    int row0 = blockIdx.x * 128;
    int nb = Nc >> 6;
    int wsel = blockIdx.y / nb;
    int col0 = (blockIdx.y % nb) * 64;
    const unsigned short* Bt = p.B[wsel];

    float4v acc[2][4] = {};

    int ra = tid >> 1;
    int ca = (tid & 1) * 16;
    int rb = tid >> 2;
    int cb = (tid & 3) * 8;

    for (int k0 = 0; k0 < K; k0 += 32) {
        {
            int grow = row0 + ra;
            uint4 a0 = make_uint4(0u, 0u, 0u, 0u), a1 = make_uint4(0u, 0u, 0u, 0u);
            if (grow < M) {
                a0 = *reinterpret_cast<const uint4*>(&A[(size_t)grow * K + k0 + ca]);
                a1 = *reinterpret_cast<const uint4*>(&A[(size_t)grow * K + k0 + ca + 8]);
            }
            *reinterpret_cast<uint4*>(&As[ra][ca]) = a0;
            *reinterpret_cast<uint4*>(&As[ra][ca + 8]) = a1;
            uint4 bv = *reinterpret_cast<const uint4*>(&Bt[(size_t)(col0 + rb) * K + k0 + cb]);
            *reinterpret_cast<uint4*>(&Bs[rb][cb]) = bv;
        }
        __syncthreads();
        short8v af[2], bf[4];
        int r16 = lane & 15;
        int kc = (lane >> 4) * 8;
        #pragma unroll
        for (int mi = 0; mi < 2; ++mi)
            af[mi] = *reinterpret_cast<const short8v*>(&As[w * 32 + mi * 16 + r16][kc]);
        #pragma unroll
        for (int nj = 0; nj < 4; ++nj)
            bf[nj] = *reinterpret_cast<const short8v*>(&Bs[nj * 16 + r16][kc]);
        #pragma unroll
        for (int mi = 0; mi < 2; ++mi)
            #pragma unroll
            for (int nj = 0; nj < 4; ++nj)
                acc[mi][nj] = __builtin_amdgcn_mfma_f32_16x16x32_bf16(af[mi], bf[nj], acc[mi][nj], 0, 0, 0);
        __syncthreads();
    }

    const float* bias = p.bias[wsel];
    int outbf = p.bf16[wsel];
    float* Cf = (float*)p.C[wsel];
    unsigned short* Cb = (unsigned short*)p.C[wsel];
    int crow_base = row0 + w * 32 + (lane >> 4) * 4;
    int ccol_base = col0 + (lane & 15);
    #pragma unroll
    for (int mi = 0; mi < 2; ++mi) {
        #pragma unroll
        for (int r = 0; r < 4; ++r) {
            int grow = crow_base + mi * 16 + r;
            if (grow >= M) continue;
            #pragma unroll
            for (int nj = 0; nj < 4; ++nj) {
                int gcol = ccol_base + nj * 16;
                float val = acc[mi][nj][r] + bias[gcol];
                if (outbf) Cb[(size_t)grow * Nc + gcol] = f2b(val);
                else       Cf[(size_t)grow * Nc + gcol] = val;
            }
        }
    }
}

// ---------------- head-combined edge aggregation (H=8), all-bf16 I/O ----------------
// One wave per node; 8-lane group per head. exp2 softmax + defer-max (T13) + 32-bit offsets
// + 2-deep register prefetch of the next 4-edge batch (T14 async-split).

__global__ __launch_bounds__(256) void agg8_kernel(const unsigned short* __restrict__ q,
                                                   const unsigned short* __restrict__ kb,
                                                   const unsigned short* __restrict__ vb,
                                                   const unsigned short* __restrict__ skip,
                                                   const int* __restrict__ offs, const int* __restrict__ csrc,
                                                   unsigned short* __restrict__ outb, int N) {
    int lane = threadIdx.x & 63;
    int node = blockIdx.x * (blockDim.x >> 6) + (threadIdx.x >> 6);
    if (node >= N) return;

    unsigned co = (unsigned)lane * 8u;
    unsigned rbase = (unsigned)node * 512u + co;
    float qv[8];
    u4tof8(*reinterpret_cast<const uint4*>(&q[rbase]), qv);

    int e0 = offs[node], e1 = offs[node + 1];
    float m = -1e30f, wsum = 0.f;
    float accv[8] = {};
    const float SC = 0.125f * 1.4426950408889634f;

    int nb4 = (e1 - e0) >> 2;   // full 4-edge batches
    uint4 ck[4], cv[4];
    if (nb4 > 0) {
        #pragma unroll
        for (int j = 0; j < 4; ++j) {
            unsigned b = (unsigned)csrc[e0 + j] * 512u + co;
            ck[j] = *reinterpret_cast<const uint4*>(&kb[b]);
            cv[j] = *reinterpret_cast<const uint4*>(&vb[b]);
        }
    }

    for (int it = 0; it < nb4; ++it) {
        uint4 nk[4], nv[4];
        bool more = (it + 1) < nb4;
        if (more) {
            int sb = e0 + (it + 1) * 4;
            #pragma unroll
            for (int j = 0; j < 4; ++j) {
                unsigned b = (unsigned)csrc[sb + j] * 512u + co;
                nk[j] = *reinterpret_cast<const uint4*>(&kb[b]);
                nv[j] = *reinterpret_cast<const uint4*>(&vb[b]);
            }
        }
        // process current batch from registers (loads above overlap this)
        float d0, d1, d2, d3;
        {
            float kk[8];
            u4tof8(ck[0], kk); d0 = 0.f;
            #pragma unroll
            for (int j = 0; j < 8; ++j) d0 += qv[j] * kk[j];
            u4tof8(ck[1], kk); d1 = 0.f;
            #pragma unroll
            for (int j = 0; j < 8; ++j) d1 += qv[j] * kk[j];
            u4tof8(ck[2], kk); d2 = 0.f;
            #pragma unroll
            for (int j = 0; j < 8; ++j) d2 += qv[j] * kk[j];
            u4tof8(ck[3], kk); d3 = 0.f;
            #pragma unroll
            for (int j = 0; j < 8; ++j) d3 += qv[j] * kk[j];
        }
        d0 += __shfl_xor(d0, 1); d1 += __shfl_xor(d1, 1); d2 += __shfl_xor(d2, 1); d3 += __shfl_xor(d3, 1);
        d0 += __shfl_xor(d0, 2); d1 += __shfl_xor(d1, 2); d2 += __shfl_xor(d2, 2); d3 += __shfl_xor(d3, 2);
        d0 += __shfl_xor(d0, 4); d1 += __shfl_xor(d1, 4); d2 += __shfl_xor(d2, 4); d3 += __shfl_xor(d3, 4);
        float a0 = d0 * SC, a1 = d1 * SC, a2 = d2 * SC, a3 = d3 * SC;
        float am = fmaxf(fmaxf(a0, a1), fmaxf(a2, a3));
        if (__any(am > m + 8.f)) {
            float mnew = fmaxf(m, am);
            float corr = exp2f(m - mnew);
            wsum *= corr;
            #pragma unroll
            for (int j = 0; j < 8; ++j) accv[j] *= corr;
            m = mnew;
        }
        float x0 = exp2f(a0 - m);
        float x1 = exp2f(a1 - m);
        float x2 = exp2f(a2 - m);
        float x3 = exp2f(a3 - m);
        wsum += (x0 + x1) + (x2 + x3);
        {
            float vv[8];
            u4tof8(cv[0], vv);
            #pragma unroll
            for (int j = 0; j < 8; ++j) accv[j] += x0 * vv[j];
            u4tof8(cv[1], vv);
            #pragma unroll
            for (int j = 0; j < 8; ++j) accv[j] += x1 * vv[j];
            u4tof8(cv[2], vv);
            #pragma unroll
            for (int j = 0; j < 8; ++j) accv[j] += x2 * vv[j];
            u4tof8(cv[3], vv);
            #pragma unroll
            for (int j = 0; j < 8; ++j) accv[j] += x3 * vv[j];
        }
        if (more) {
            #pragma unroll
            for (int j = 0; j < 4; ++j) { ck[j] = nk[j]; cv[j] = nv[j]; }
        }
    }

    // remainder edges
    for (int s = e0 + nb4 * 4; s < e1; ++s) {
        unsigned b0 = (unsigned)csrc[s] * 512u + co;
        float kk0[8], vv0[8];
        u4tof8(*reinterpret_cast<const uint4*>(&kb[b0]), kk0);
        u4tof8(*reinterpret_cast<const uint4*>(&vb[b0]), vv0);
        float d0 = 0.f;
        #pragma unroll
        for (int j = 0; j < 8; ++j) d0 += qv[j] * kk0[j];
        d0 += __shfl_xor(d0, 1);
        d0 += __shfl_xor(d0, 2);
        d0 += __shfl_xor(d0, 4);
        float a0 = d0 * SC;
        if (__any(a0 > m + 8.f)) {
            float mnew = fmaxf(m, a0);
            float corr = exp2f(m - mnew);
            wsum *= corr;
            #pragma unroll
            for (int j = 0; j < 8; ++j) accv[j] *= corr;
            m = mnew;
        }
        float x0 = exp2f(a0 - m);
        wsum += x0;
        #pragma unroll
        for (int j = 0; j < 8; ++j) accv[j] += x0 * vv0[j];
    }

    float inv = (e1 > e0) ? (1.0f / wsum) : 0.f;
    float sk[8];
    u4tof8(*reinterpret_cast<const uint4*>(&skip[rbase]), sk);
    ushort4 o0, o1;
    o0.x = f2b(fmaxf(sk[0] + accv[0] * inv, 0.f));
    o0.y = f2b(fmaxf(sk[1] + accv[1] * inv, 0.f));
    o0.z = f2b(fmaxf(sk[2] + accv[2] * inv, 0.f));
    o0.w = f2b(fmaxf(sk[3] + accv[3] * inv, 0.f));
    o1.x = f2b(fmaxf(sk[4] + accv[4] * inv, 0.f));
    o1.y = f2b(fmaxf(sk[5] + accv[5] * inv, 0.f));
    o1.z = f2b(fmaxf(sk[6] + accv[6] * inv, 0.f));
    o1.w = f2b(fmaxf(sk[7] + accv[7] * inv, 0.f));
    *reinterpret_cast<ushort4*>(&outb[rbase]) = o0;
    *reinterpret_cast<ushort4*>(&outb[rbase + 4]) = o1;
}

// ---------------- final-layer aggregation (H=1), q bf16, fp32 out ----------------

__global__ __launch_bounds__(256) void aggf_kernel(const unsigned short* __restrict__ q,
                                                   const unsigned short* __restrict__ kb,
                                                   const unsigned short* __restrict__ vb,
                                                   const int* __restrict__ offs, const int* __restrict__ csrc,
                                                   float* __restrict__ out, int N) {
    const int HC = 64;
    int lane = threadIdx.x & 63;
    int node = blockIdx.x * (blockDim.x >> 6) + (threadIdx.x >> 6);
    if (node >= N) return;
    int g = lane >> 4;
    int r = lane & 15;

    unsigned qbase = (unsigned)node * 64u + 4u * r;
    ushort4 q4u = *reinterpret_cast<const ushort4*>(&q[qbase]);
    float q4[4] = {b2f(q4u.x), b2f(q4u.y), b2f(q4u.z), b2f(q4u.w)};

    int e0 = offs[node], e1 = offs[node + 1];
    float m = -3.4e38f, wsum = 0.f;
    float accv[4] = {0.f, 0.f, 0.f, 0.f};

    int nIt = (e1 - e0 + 3) >> 2;
    for (int it = 0; it < nIt; ++it) {
        int s = e0 + it * 4 + g;
        bool valid = s < e1;
        unsigned base = (unsigned)csrc[valid ? s : (e1 - 1)] * 64u + 4u * r;
        ushort4 k4 = *reinterpret_cast<const ushort4*>(&kb[base]);
        float d = q4[0] * b2f(k4.x) + q4[1] * b2f(k4.y) + q4[2] * b2f(k4.z) + q4[3] * b2f(k4.w);
        d += __shfl_xor(d, 1);
        d += __shfl_xor(d, 2);
        d += __shfl_xor(d, 4);
        d += __shfl_xor(d, 8);
        float alpha = valid ? d * 0.125f : -3.4e38f;
        float am = fmaxf(alpha, __shfl_xor(alpha, 16));
        am = fmaxf(am, __shfl_xor(am, 32));
        float mnew = fmaxf(m, am);
        float corr = __expf(m - mnew);
        float ex = __expf(alpha - mnew);
        ushort4 v4 = *reinterpret_cast<const ushort4*>(&vb[base]);
        wsum = wsum * corr + ex;
        accv[0] = accv[0] * corr + ex * b2f(v4.x);
        accv[1] = accv[1] * corr + ex * b2f(v4.y);
        accv[2] = accv[2] * corr + ex * b2f(v4.z);
        accv[3] = accv[3] * corr + ex * b2f(v4.w);
        m = mnew;
    }

    #pragma unroll
    for (int off = 16; off <= 32; off <<= 1) {
        wsum += __shfl_xor(wsum, off);
        #pragma unroll
        for (int j = 0; j < 4; ++j) accv[j] += __shfl_xor(accv[j], off);
    }

    if (g == 0) {
        float inv = (e1 > e0) ? (1.0f / wsum) : 0.f;
        float4 o = *reinterpret_cast<const float4*>(&out[qbase]);
        o.x += accv[0] * inv;
        o.y += accv[1] * inv;
        o.z += accv[2] * inv;
        o.w += accv[3] * inv;
        *reinterpret_cast<float4*>(&out[qbase]) = o;
    }
}

// ---------------- mean pool + MLP head ----------------

__global__ void pool_kernel(const float* __restrict__ hin, float* __restrict__ g, int N) {
    int dim = blockIdx.x;
    float s = 0.f;
    for (int i = threadIdx.x; i < N; i += blockDim.x) s += hin[(size_t)i * 64 + dim];
    __shared__ float red[256];
    red[threadIdx.x] = s;
    __syncthreads();
    for (int d = 128; d >= 1; d >>= 1) {
        if ((int)threadIdx.x < d) red[threadIdx.x] += red[threadIdx.x + d];
        __syncthreads();
    }
    if (threadIdx.x == 0) g[dim] = red[0] / (float)N;
}

__global__ void mlp_kernel(const float* __restrict__ g, const float* __restrict__ Wc1,
                           const float* __restrict__ bc1, const float* __restrict__ Wc2,
                           const float* __restrict__ bc2, float* __restrict__ out) {
    __shared__ float gs[64];
    __shared__ float h1[32];
    int t = threadIdx.x;
    if (t < 64) gs[t] = g[t];
    __syncthreads();
    if (t < 32) {
        float s = bc1[t];
        for (int i = 0; i < 64; ++i) s += gs[i] * Wc1[i * 32 + t];
        h1[t] = fmaxf(s, 0.f);
    }
    __syncthreads();
    if (t < 2) {
        float s = bc2[t];
        for (int i = 0; i < 32; ++i) s += h1[i] * Wc2[i * 2 + t];
        out[t] = s;
    }
}

// ---------------- launch ----------------

extern "C" void kernel_launch(void* const* d_in, const int* in_sizes, int n_in,
                              void* d_out, int out_size, void* d_ws, size_t ws_size,
                              hipStream_t stream) {
    const float* x   = (const float*)d_in[0];
    const int*   ei  = (const int*)d_in[1];
    const float* Wp  = (const float*)d_in[2];
    const float* bp  = (const float*)d_in[3];
    const float* Wq0 = (const float*)d_in[4];
    const float* Wk0 = (const float*)d_in[5];
    const float* Wv0 = (const float*)d_in[6];
    const float* Ws0 = (const float*)d_in[7];
    const float* bq0 = (const float*)d_in[8];
    const float* bk0 = (const float*)d_in[9];
    const float* bv0 = (const float*)d_in[10];
    const float* bs0 = (const float*)d_in[11];
    const float* Wq  = (const float*)d_in[12];
    const float* Wk  = (const float*)d_in[13];
    const float* Wv  = (const float*)d_in[14];
    const float* Ws  = (const float*)d_in[15];
    const float* bq  = (const float*)d_in[16];
    const float* bk  = (const float*)d_in[17];
    const float* bv  = (const float*)d_in[18];
    const float* bs  = (const float*)d_in[19];
    const float* Wqf = (const float*)d_in[20];
    const float* Wkf = (const float*)d_in[21];
    const float* Wvf = (const float*)d_in[22];
    const float* Wsf = (const float*)d_in[23];
    const float* bqf = (const float*)d_in[24];
    const float* bkf = (const float*)d_in[25];
    const float* bvf = (const float*)d_in[26];
    const float* bsf = (const float*)d_in[27];
    const float* Wc1 = (const float*)d_in[28];
    const float* bc1 = (const float*)d_in[29];
    const float* Wc2 = (const float*)d_in[30];
    const float* bc2 = (const float*)d_in[31];

    const int N = in_sizes[0] / 256;
    const int E = in_sizes[1] / 2;
    const int HC = 512;

    size_t NB = (size_t)N * HC;
    const size_t WSMALL = 64 * 256 + 8 * 512 * 64;
    size_t need = 6 * NB * sizeof(unsigned short)
                + (size_t)16 * 512 * 512 * sizeof(unsigned short)
                + WSMALL * sizeof(unsigned short)
                + NB * sizeof(float)
                + (size_t)(2 * N + 1 + E) * sizeof(int)
                + 64 * sizeof(float) + 4096;
    if (ws_size < need) return;

    unsigned short* h0    = (unsigned short*)d_ws;
    unsigned short* h1    = h0 + NB;
    unsigned short* qb16  = h1 + NB;
    unsigned short* kb    = qb16 + NB;
    unsigned short* vb    = kb + NB;
    unsigned short* skipb = vb + NB;
    unsigned short* wt16  = skipb + NB;
    unsigned short* wsm   = wt16 + (size_t)16 * 512 * 512;
    uintptr_t pa = (uintptr_t)(wsm + WSMALL);
    pa = (pa + 255) & ~(uintptr_t)255;
    float* hf32 = (float*)pa;
    int* offs   = (int*)(hf32 + NB);
    int* cursor = offs + (N + 1);
    int* csrc   = cursor + N;
    float* gbuf = (float*)(csrc + E);
    int*   bsum = (int*)(gbuf + 64);
    unsigned short* xb = qb16;  // alias: qb16 free until layer 0 writes it

    int nsb = cdiv(N, 256);

    // --- CSR build (by dst), hierarchical scan ---
    hipMemsetAsync(cursor, 0, sizeof(int) * N, stream);
    count_kernel<<<cdiv(E, 256), 256, 0, stream>>>(ei, cursor, E);
    scan1_kernel<<<nsb, 256, 0, stream>>>(cursor, offs, bsum, N);
    scan2_kernel<<<1, 64, 0, stream>>>(bsum, offs, nsb);
    scan3_kernel<<<nsb, 256, 0, stream>>>(offs, bsum, N);
    hipMemsetAsync(cursor, 0, sizeof(int) * N, stream);
    fill_kernel<<<cdiv(E, 256), 256, 0, stream>>>(ei, offs, cursor, csrc, E);

    // --- weight prep ---
    transpose_b16_kernel<<<dim3(16, 16, 16), dim3(32, 8), 0, stream>>>(Wq, Wk, Wv, Ws, wt16);
    {
        SmallT st;
        unsigned short* wp_t = wsm;
        unsigned short* w0_t = wsm + 64 * 256;
        unsigned short* wf_t = w0_t + 4 * 512 * 64;
        st.src[0] = Wp;  st.dst[0] = wp_t; st.rows[0] = 256; st.cols[0] = 64;
        const float* w0s[4] = {Wq0, Wk0, Wv0, Ws0};
        const float* wfs[4] = {Wqf, Wkf, Wvf, Wsf};
        for (int i = 0; i < 4; ++i) {
            st.src[1 + i] = w0s[i]; st.dst[1 + i] = w0_t + i * 512 * 64;
            st.rows[1 + i] = 64; st.cols[1 + i] = 512;
            st.src[5 + i] = wfs[i]; st.dst[5 + i] = wf_t + i * 64 * 512;
            st.rows[5 + i] = 512; st.cols[5 + i] = 64;
        }
        transpose_small_kernel<<<dim3(32, 9), dim3(32, 8), 0, stream>>>(st);
    }

    // --- input projection: h0 = bf16(x @ Wp + bp)  [N,64] ---
    f2b_kernel<<<1280, 256, 0, stream>>>(x, xb, N * 256 / 4);
    {
        GemmPtrs gp;
        for (int j = 0; j < 4; ++j) {
            gp.B[j] = wsm; gp.bias[j] = bp; gp.C[j] = h0; gp.bf16[j] = 1;
        }
        mfma_flex<<<dim3(cdiv(N, 128), 1), 256, 0, stream>>>(xb, gp, N, 256, 64);
    }

    // --- layer 0: 64 -> 512 (H=8, concat) ---
    {
        GemmPtrs gp;
        unsigned short* w0_t = wsm + 64 * 256;
        gp.B[0] = w0_t + 0 * 512 * 64; gp.bias[0] = bq0; gp.C[0] = qb16;  gp.bf16[0] = 1;
        gp.B[1] = w0_t + 1 * 512 * 64; gp.bias[1] = bk0; gp.C[1] = kb;    gp.bf16[1] = 1;
        gp.B[2] = w0_t + 2 * 512 * 64; gp.bias[2] = bv0; gp.C[2] = vb;    gp.bf16[2] = 1;
        gp.B[3] = w0_t + 3 * 512 * 64; gp.bias[3] = bs0; gp.C[3] = skipb; gp.bf16[3] = 1;
        mfma_flex<<<dim3(cdiv(N, 128), 4 * 8), 256, 0, stream>>>(h0, gp, N, 64, 512);
    }
    agg8_kernel<<<cdiv(N, 4), 256, 0, stream>>>(qb16, kb, vb, skipb, offs, csrc, h1, N);

    // --- layers 1..4: 512 -> 512, fused q/k/v/s MFMA (all-bf16 chain) ---
    unsigned short* hcur = h1;
    unsigned short* hnext = h0;
    int gx = cdiv(N, 128);
    for (int l = 0; l < 4; ++l) {
        GemmPtrs gp;
        gp.B[0] = wt16 + (size_t)(l * 4 + 0) * 512 * 512;
        gp.B[1] = wt16 + (size_t)(l * 4 + 1) * 512 * 512;
        gp.B[2] = wt16 + (size_t)(l * 4 + 2) * 512 * 512;
        gp.B[3] = wt16 + (size_t)(l * 4 + 3) * 512 * 512;
        gp.bias[0] = bq + l * HC;
        gp.bias[1] = bk + l * HC;
        gp.bias[2] = bv + l * HC;
        gp.bias[3] = bs + l * HC;
        gp.C[0] = qb16; gp.C[1] = kb; gp.C[2] = vb; gp.C[3] = skipb;
        gp.bf16[0] = 1; gp.bf16[1] = 1; gp.bf16[2] = 1; gp.bf16[3] = 1;
        mfma_gemm4<<<gx * 16, 256, 0, stream>>>(hcur, gp, N, gx * 16);
        agg8_kernel<<<cdiv(N, 4), 256, 0, stream>>>(qb16, kb, vb, skipb, offs, csrc, hnext, N);
        { unsigned short* t = hcur; hcur = hnext; hnext = t; }
    }

    // --- final layer: 512 -> 64 (H=1, no concat, no relu) ---
    {
        GemmPtrs gp;
        unsigned short* wf_t = wsm + 64 * 256 + 4 * 512 * 64;
        gp.B[0] = wf_t + 0 * 64 * 512; gp.bias[0] = bqf; gp.C[0] = qb16; gp.bf16[0] = 1;
        gp.B[1] = wf_t + 1 * 64 * 512; gp.bias[1] = bkf; gp.C[1] = kb;   gp.bf16[1] = 1;
        gp.B[2] = wf_t + 2 * 64 * 512; gp.bias[2] = bvf; gp.C[2] = vb;   gp.bf16[2] = 1;
        gp.B[3] = wf_t + 3 * 64 * 512; gp.bias[3] = bsf; gp.C[3] = hf32; gp.bf16[3] = 0;
        mfma_flex<<<dim3(cdiv(N, 128), 4), 256, 0, stream>>>(hcur, gp, N, 512, 64);
    }
    aggf_kernel<<<cdiv(N, 4), 256, 0, stream>>>(qb16, kb, vb, offs, csrc, hf32, N);

    // --- mean pool + MLP ---
    pool_kernel<<<64, 256, 0, stream>>>(hf32, gbuf, N);
    mlp_kernel<<<1, 64, 0, stream>>>(gbuf, Wc1, bc1, Wc2, bc2, (float*)d_out);
}

// Round 16
// 567.233 us; speedup vs baseline: 1.0096x; 1.0096x over previous
//
#include <hip/hip_runtime.h>
#include <hip/hip_bf16.h>
#include <cstddef>
#include <cstdint>

static inline int cdiv(int a, int b) { return (a + b - 1) / b; }

typedef short short8v __attribute__((ext_vector_type(8)));
typedef float float4v __attribute__((ext_vector_type(4)));

__device__ inline unsigned short f2b(float f) {
    union { float f; unsigned u; } x; x.f = f;
    unsigned u = x.u;
    return (unsigned short)((u + 0x7fff + ((u >> 16) & 1)) >> 16);
}

__device__ inline float lo2f(unsigned u) { union { unsigned x; float f; } c; c.x = u << 16; return c.f; }
__device__ inline float hi2f(unsigned u) { union { unsigned x; float f; } c; c.x = u & 0xffff0000u; return c.f; }
__device__ inline float b2f(unsigned short b) {
    union { unsigned u; float f; } x; x.u = ((unsigned)b) << 16;
    return x.f;
}

__device__ __forceinline__ void u4tof8(uint4 u, float* f) {
    f[0] = lo2f(u.x); f[1] = hi2f(u.x); f[2] = lo2f(u.y); f[3] = hi2f(u.y);
    f[4] = lo2f(u.z); f[5] = hi2f(u.z); f[6] = lo2f(u.w); f[7] = hi2f(u.w);
}

// async global -> LDS, 16 bytes per lane (wave-uniform LDS base + lane*16)
__device__ __forceinline__ void gload_lds16(const unsigned short* g, unsigned short* lds) {
    __builtin_amdgcn_global_load_lds(
        (const __attribute__((address_space(1))) unsigned int*)g,
        (__attribute__((address_space(3))) unsigned int*)lds, 16, 0, 0);
}

// ---------------- CSR build ----------------

__global__ void count_kernel(const int* __restrict__ ei, int* __restrict__ indeg, int E) {
    int e = blockIdx.x * blockDim.x + threadIdx.x;
    if (e < E) atomicAdd(&indeg[ei[E + e]], 1);
}

__global__ void scan1_kernel(const int* __restrict__ deg, int* __restrict__ offs,
                             int* __restrict__ bsum, int n) {
    __shared__ int tmp[256];
    int i = blockIdx.x * 256 + threadIdx.x;
    int v = (i < n) ? deg[i] : 0;
    tmp[threadIdx.x] = v;
    __syncthreads();
    for (int d = 1; d < 256; d <<= 1) {
        int a = (threadIdx.x >= (unsigned)d) ? tmp[threadIdx.x - d] : 0;
        __syncthreads();
        tmp[threadIdx.x] += a;
        __syncthreads();
    }
    if (i < n) offs[i + 1] = tmp[threadIdx.x];
    if (threadIdx.x == 255) bsum[blockIdx.x] = tmp[255];
}

__global__ void scan2_kernel(int* __restrict__ bsum, int* __restrict__ offs, int nb) {
    if (threadIdx.x == 0) {
        offs[0] = 0;
        int base = 0;
        for (int b = 0; b < nb; ++b) { int t = bsum[b]; bsum[b] = base; base += t; }
    }
}

__global__ void scan3_kernel(int* __restrict__ offs, const int* __restrict__ bsum, int n) {
    int i = blockIdx.x * 256 + threadIdx.x;
    if (i < n) offs[i + 1] += bsum[blockIdx.x];
}

__global__ void fill_kernel(const int* __restrict__ ei, const int* __restrict__ offs,
                            int* __restrict__ cursor, int* __restrict__ csrc, int E) {
    int e = blockIdx.x * blockDim.x + threadIdx.x;
    if (e < E) {
        int d = ei[E + e];
        int s = ei[e];
        int pos = atomicAdd(&cursor[d], 1);
        csrc[offs[d] + pos] = s;
    }
}

// ---------------- fp32 -> bf16 ----------------

__global__ void f2b_kernel(const float* __restrict__ in, unsigned short* __restrict__ out, int n4) {
    int stride = gridDim.x * blockDim.x;
    for (int i = blockIdx.x * blockDim.x + threadIdx.x; i < n4; i += stride) {
        float4 v = reinterpret_cast<const float4*>(in)[i];
        ushort4 o;
        o.x = f2b(v.x); o.y = f2b(v.y); o.z = f2b(v.z); o.w = f2b(v.w);
        reinterpret_cast<ushort4*>(out)[i] = o;
    }
}

// Transpose+convert 16 big weights [512][512] fp32 -> bf16 [Nc][K].
__global__ void transpose_b16_kernel(const float* __restrict__ Wq, const float* __restrict__ Wk,
                                     const float* __restrict__ Wv, const float* __restrict__ Ws,
                                     unsigned short* __restrict__ out) {
    const int K = 512, Nc = 512;
    int z = blockIdx.z;
    int which = z & 3;
    const float* W = (which == 0) ? Wq : (which == 1) ? Wk : (which == 2) ? Wv : Ws;
    W += (size_t)(z >> 2) * K * Nc;
    unsigned short* Wt = out + (size_t)z * K * Nc;
    __shared__ float t[32][33];
    int k0 = blockIdx.x * 32, c0 = blockIdx.y * 32;
    int tx = threadIdx.x, ty = threadIdx.y;
    #pragma unroll
    for (int i = 0; i < 32; i += 8) t[ty + i][tx] = W[(size_t)(k0 + ty + i) * Nc + c0 + tx];
    __syncthreads();
    #pragma unroll
    for (int i = 0; i < 32; i += 8) Wt[(size_t)(c0 + ty + i) * K + k0 + tx] = f2b(t[tx][ty + i]);
}

// Batched transpose of 9 small weights.
struct SmallT {
    const float* src[9];
    unsigned short* dst[9];
    int rows[9];
    int cols[9];
};

__global__ void transpose_small_kernel(SmallT p) {
    int mat = blockIdx.y;
    int rows = p.rows[mat], cols = p.cols[mat];
    int tilesC = cols >> 5;
    int tiles = (rows >> 5) * tilesC;
    if ((int)blockIdx.x >= tiles) return;
    int tr = blockIdx.x / tilesC, tc = blockIdx.x % tilesC;
    const float* src = p.src[mat];
    unsigned short* dst = p.dst[mat];
    __shared__ float t[32][33];
    int r0 = tr * 32, c0 = tc * 32;
    int tx = threadIdx.x, ty = threadIdx.y;
    #pragma unroll
    for (int i = 0; i < 32; i += 8) t[ty + i][tx] = src[(size_t)(r0 + ty + i) * cols + c0 + tx];
    __syncthreads();
    #pragma unroll
    for (int i = 0; i < 32; i += 8) dst[(size_t)(c0 + ty + i) * rows + r0 + tx] = f2b(t[tx][ty + i]);
}

// ---------------- fused bf16 MFMA GEMM (512x512), 3-deep counted-vmcnt pipeline ----------------
// BK=32, 3 LDS buffers. Per iter: vmcnt(8) (wait ONLY current tile; 2 tiles stay in flight)
// -> raw s_barrier -> ds_read+MFMA -> raw s_barrier -> issue tile i+3 into freed buffer.
// Never drains vmcnt to 0 in steady state (T4). T2 slot-swizzle retained (conflicts = 0).

struct GemmPtrs {
    const unsigned short* B[4];
    const float* bias[4];
    void* C[4];
    int bf16[4];
};

__global__ __launch_bounds__(256) void mfma_gemm4(const unsigned short* __restrict__ A,
                                                  GemmPtrs p, int M, int nb) {
    __shared__ unsigned short As[3][128 * 32];
    __shared__ unsigned short Bs[3][128 * 32];
    int i = blockIdx.x;
    int wk = (nb & 7) ? i : ((i & 7) * (nb >> 3) + (i >> 3));  // T1 XCD swizzle
    int xt = wk >> 4, yt = wk & 15;
    int row0 = xt * 128;
    int wsel = yt >> 2;
    int col0 = (yt & 3) * 128;
    const unsigned short* Bt = p.B[wsel];

    int tid = threadIdx.x;
    int lane = tid & 63;
    int w = tid >> 6;
    int wr = w >> 1, wc = w & 1;
    float4v acc[4][4] = {};

    int c0i = w * 2;
    int srow0 = c0i * 16 + (lane >> 2);
    int srow1 = srow0 + 16;
    int sslot0 = (lane & 3) ^ ((srow0 >> 1) & 3);   // T2 pre-swizzled 16B slot
    int sslot1 = (lane & 3) ^ ((srow1 >> 1) & 3);

    const unsigned short* Ag0 = A + (size_t)(row0 + srow0) * 512 + sslot0 * 8;
    const unsigned short* Ag1 = A + (size_t)(row0 + srow1) * 512 + sslot1 * 8;
    const unsigned short* Bg0 = Bt + (size_t)(col0 + srow0) * 512 + sslot0 * 8;
    const unsigned short* Bg1 = Bt + (size_t)(col0 + srow1) * 512 + sslot1 * 8;

    // prologue: prefetch tiles 0..2 (12 loads in flight per thread)
    #pragma unroll
    for (int t = 0; t < 3; ++t) {
        gload_lds16(Ag0 + t * 32, &As[t][c0i * 512]);
        gload_lds16(Ag1 + t * 32, &As[t][(c0i + 1) * 512]);
        gload_lds16(Bg0 + t * 32, &Bs[t][c0i * 512]);
        gload_lds16(Bg1 + t * 32, &Bs[t][(c0i + 1) * 512]);
    }

    int r16 = lane & 15;
    int ks = lane >> 4;

    #pragma unroll
    for (int kt = 0; kt < 16; ++kt) {
        if (kt <= 13)      { asm volatile("s_waitcnt vmcnt(8)" ::: "memory"); }
        else if (kt == 14) { asm volatile("s_waitcnt vmcnt(4)" ::: "memory"); }
        else               { asm volatile("s_waitcnt vmcnt(0)" ::: "memory"); }
        __builtin_amdgcn_sched_barrier(0);
        __builtin_amdgcn_s_barrier();        // all waves' tile-kt loads landed
        int buf = kt % 3;
        short8v af[4], bf[4];
        #pragma unroll
        for (int mi = 0; mi < 4; ++mi) {
            int row = wr * 64 + mi * 16 + r16;
            int slot = ks ^ ((row >> 1) & 3);
            af[mi] = *reinterpret_cast<const short8v*>(&As[buf][row * 32 + slot * 8]);
        }
        #pragma unroll
        for (int nj = 0; nj < 4; ++nj) {
            int row = wc * 64 + nj * 16 + r16;
            int slot = ks ^ ((row >> 1) & 3);
            bf[nj] = *reinterpret_cast<const short8v*>(&Bs[buf][row * 32 + slot * 8]);
        }
        #pragma unroll
        for (int mi = 0; mi < 4; ++mi)
            #pragma unroll
            for (int nj = 0; nj < 4; ++nj)
                acc[mi][nj] = __builtin_amdgcn_mfma_f32_16x16x32_bf16(af[mi], bf[nj], acc[mi][nj], 0, 0, 0);
        __builtin_amdgcn_s_barrier();        // all reads of buf done -> safe to overwrite
        if (kt <= 12) {
            int nk = (kt + 3) * 32;
            gload_lds16(Ag0 + nk, &As[buf][c0i * 512]);
            gload_lds16(Ag1 + nk, &As[buf][(c0i + 1) * 512]);
            gload_lds16(Bg0 + nk, &Bs[buf][c0i * 512]);
            gload_lds16(Bg1 + nk, &Bs[buf][(c0i + 1) * 512]);
        }
    }

    const float* bias = p.bias[wsel];
    int outbf = p.bf16[wsel];
    float* Cf = (float*)p.C[wsel];
    unsigned short* Cb = (unsigned short*)p.C[wsel];
    int crow_base = row0 + wr * 64 + (lane >> 4) * 4;
    int ccol_base = col0 + wc * 64 + (lane & 15);
    #pragma unroll
    for (int mi = 0; mi < 4; ++mi) {
        #pragma unroll
        for (int r = 0; r < 4; ++r) {
            int grow = crow_base + mi * 16 + r;
            if (grow >= M) continue;
            #pragma unroll
            for (int nj = 0; nj < 4; ++nj) {
                int gcol = ccol_base + nj * 16;
                float val = acc[mi][nj][r] + bias[gcol];
                if (outbf) Cb[(size_t)grow * 512 + gcol] = f2b(val);
                else       Cf[(size_t)grow * 512 + gcol] = val;
            }
        }
    }
}

// ---------------- flexible MFMA GEMM: BM=128, BN=64, BK=32, runtime K/N ----------------

__global__ __launch_bounds__(256) void mfma_flex(const unsigned short* __restrict__ A,
                                                 GemmPtrs p, int M, int K, int Nc) {
    __shared__ unsigned short As[128][40];
    __shared__ unsigned short Bs[64][40];
    int tid = threadIdx.x;
    int lane = tid & 63;
    int w = tid >> 6;
    int row0 = blockIdx.x * 128;
    int nb = Nc >> 6;
    int wsel = blockIdx.y / nb;
    int col0 = (blockIdx.y % nb) * 64;
    const unsigned short* Bt = p.B[wsel];

    float4v acc[2][4] = {};

    int ra = tid >> 1;
    int ca = (tid & 1) * 16;
    int rb = tid >> 2;
    int cb = (tid & 3) * 8;

    for (int k0 = 0; k0 < K; k0 += 32) {
        {
            int grow = row0 + ra;
            uint4 a0 = make_uint4(0u, 0u, 0u, 0u), a1 = make_uint4(0u, 0u, 0u, 0u);
            if (grow < M) {
                a0 = *reinterpret_cast<const uint4*>(&A[(size_t)grow * K + k0 + ca]);
                a1 = *reinterpret_cast<const uint4*>(&A[(size_t)grow * K + k0 + ca + 8]);
            }
            *reinterpret_cast<uint4*>(&As[ra][ca]) = a0;
            *reinterpret_cast<uint4*>(&As[ra][ca + 8]) = a1;
            uint4 bv = *reinterpret_cast<const uint4*>(&Bt[(size_t)(col0 + rb) * K + k0 + cb]);
            *reinterpret_cast<uint4*>(&Bs[rb][cb]) = bv;
        }
        __syncthreads();
        short8v af[2], bf[4];
        int r16 = lane & 15;
        int kc = (lane >> 4) * 8;
        #pragma unroll
        for (int mi = 0; mi < 2; ++mi)
            af[mi] = *reinterpret_cast<const short8v*>(&As[w * 32 + mi * 16 + r16][kc]);
        #pragma unroll
        for (int nj = 0; nj < 4; ++nj)
            bf[nj] = *reinterpret_cast<const short8v*>(&Bs[nj * 16 + r16][kc]);
        #pragma unroll
        for (int mi = 0; mi < 2; ++mi)
            #pragma unroll
            for (int nj = 0; nj < 4; ++nj)
                acc[mi][nj] = __builtin_amdgcn_mfma_f32_16x16x32_bf16(af[mi], bf[nj], acc[mi][nj], 0, 0, 0);
        __syncthreads();
    }

    const float* bias = p.bias[wsel];
    int outbf = p.bf16[wsel];
    float* Cf = (float*)p.C[wsel];
    unsigned short* Cb = (unsigned short*)p.C[wsel];
    int crow_base = row0 + w * 32 + (lane >> 4) * 4;
    int ccol_base = col0 + (lane & 15);
    #pragma unroll
    for (int mi = 0; mi < 2; ++mi) {
        #pragma unroll
        for (int r = 0; r < 4; ++r) {
            int grow = crow_base + mi * 16 + r;
            if (grow >= M) continue;
            #pragma unroll
            for (int nj = 0; nj < 4; ++nj) {
                int gcol = ccol_base + nj * 16;
                float val = acc[mi][nj][r] + bias[gcol];
                if (outbf) Cb[(size_t)grow * Nc + gcol] = f2b(val);
                else       Cf[(size_t)grow * Nc + gcol] = val;
            }
        }
    }
}

// ---------------- head-combined edge aggregation (H=8), all-bf16 I/O ----------------
// One wave per node; 8-lane group per head. exp2-domain softmax + defer-max (T13)
// + 32-bit offsets + 4-edge unroll (8 gather loads in flight per wave).

__global__ __launch_bounds__(256) void agg8_kernel(const unsigned short* __restrict__ q,
                                                   const unsigned short* __restrict__ kb,
                                                   const unsigned short* __restrict__ vb,
                                                   const unsigned short* __restrict__ skip,
                                                   const int* __restrict__ offs, const int* __restrict__ csrc,
                                                   unsigned short* __restrict__ outb, int N) {
    int lane = threadIdx.x & 63;
    int node = blockIdx.x * (blockDim.x >> 6) + (threadIdx.x >> 6);
    if (node >= N) return;

    unsigned co = (unsigned)lane * 8u;
    unsigned rbase = (unsigned)node * 512u + co;
    float qv[8];
    u4tof8(*reinterpret_cast<const uint4*>(&q[rbase]), qv);

    int e0 = offs[node], e1 = offs[node + 1];
    float m = -1e30f, wsum = 0.f;
    float accv[8] = {};
    const float SC = 0.125f * 1.4426950408889634f;

    int s = e0;
    for (; s + 4 <= e1; s += 4) {
        unsigned b0 = (unsigned)csrc[s] * 512u + co;
        unsigned b1 = (unsigned)csrc[s + 1] * 512u + co;
        unsigned b2 = (unsigned)csrc[s + 2] * 512u + co;
        unsigned b3 = (unsigned)csrc[s + 3] * 512u + co;
        uint4 k0 = *reinterpret_cast<const uint4*>(&kb[b0]);
        uint4 k1 = *reinterpret_cast<const uint4*>(&kb[b1]);
        uint4 k2 = *reinterpret_cast<const uint4*>(&kb[b2]);
        uint4 k3 = *reinterpret_cast<const uint4*>(&kb[b3]);
        uint4 v0 = *reinterpret_cast<const uint4*>(&vb[b0]);
        uint4 v1 = *reinterpret_cast<const uint4*>(&vb[b1]);
        uint4 v2 = *reinterpret_cast<const uint4*>(&vb[b2]);
        uint4 v3 = *reinterpret_cast<const uint4*>(&vb[b3]);
        float kk0[8], kk1[8], kk2[8], kk3[8];
        u4tof8(k0, kk0); u4tof8(k1, kk1); u4tof8(k2, kk2); u4tof8(k3, kk3);
        float d0 = 0.f, d1 = 0.f, d2 = 0.f, d3 = 0.f;
        #pragma unroll
        for (int j = 0; j < 8; ++j) {
            d0 += qv[j] * kk0[j]; d1 += qv[j] * kk1[j];
            d2 += qv[j] * kk2[j]; d3 += qv[j] * kk3[j];
        }
        d0 += __shfl_xor(d0, 1); d1 += __shfl_xor(d1, 1); d2 += __shfl_xor(d2, 1); d3 += __shfl_xor(d3, 1);
        d0 += __shfl_xor(d0, 2); d1 += __shfl_xor(d1, 2); d2 += __shfl_xor(d2, 2); d3 += __shfl_xor(d3, 2);
        d0 += __shfl_xor(d0, 4); d1 += __shfl_xor(d1, 4); d2 += __shfl_xor(d2, 4); d3 += __shfl_xor(d3, 4);
        float a0 = d0 * SC, a1 = d1 * SC, a2 = d2 * SC, a3 = d3 * SC;
        float am = fmaxf(fmaxf(a0, a1), fmaxf(a2, a3));
        if (__any(am > m + 8.f)) {
            float mnew = fmaxf(m, am);
            float corr = exp2f(m - mnew);
            wsum *= corr;
            #pragma unroll
            for (int j = 0; j < 8; ++j) accv[j] *= corr;
            m = mnew;
        }
        float x0 = exp2f(a0 - m);
        float x1 = exp2f(a1 - m);
        float x2 = exp2f(a2 - m);
        float x3 = exp2f(a3 - m);
        wsum += (x0 + x1) + (x2 + x3);
        float vv0[8], vv1[8], vv2[8], vv3[8];
        u4tof8(v0, vv0); u4tof8(v1, vv1); u4tof8(v2, vv2); u4tof8(v3, vv3);
        #pragma unroll
        for (int j = 0; j < 8; ++j)
            accv[j] += (x0 * vv0[j] + x1 * vv1[j]) + (x2 * vv2[j] + x3 * vv3[j]);
    }
    for (; s < e1; ++s) {
        unsigned b0 = (unsigned)csrc[s] * 512u + co;
        float kk0[8], vv0[8];
        u4tof8(*reinterpret_cast<const uint4*>(&kb[b0]), kk0);
        u4tof8(*reinterpret_cast<const uint4*>(&vb[b0]), vv0);
        float d0 = 0.f;
        #pragma unroll
        for (int j = 0; j < 8; ++j) d0 += qv[j] * kk0[j];
        d0 += __shfl_xor(d0, 1);
        d0 += __shfl_xor(d0, 2);
        d0 += __shfl_xor(d0, 4);
        float a0 = d0 * SC;
        if (__any(a0 > m + 8.f)) {
            float mnew = fmaxf(m, a0);
            float corr = exp2f(m - mnew);
            wsum *= corr;
            #pragma unroll
            for (int j = 0; j < 8; ++j) accv[j] *= corr;
            m = mnew;
        }
        float x0 = exp2f(a0 - m);
        wsum += x0;
        #pragma unroll
        for (int j = 0; j < 8; ++j) accv[j] += x0 * vv0[j];
    }

    float inv = (e1 > e0) ? (1.0f / wsum) : 0.f;
    float sk[8];
    u4tof8(*reinterpret_cast<const uint4*>(&skip[rbase]), sk);
    ushort4 o0, o1;
    o0.x = f2b(fmaxf(sk[0] + accv[0] * inv, 0.f));
    o0.y = f2b(fmaxf(sk[1] + accv[1] * inv, 0.f));
    o0.z = f2b(fmaxf(sk[2] + accv[2] * inv, 0.f));
    o0.w = f2b(fmaxf(sk[3] + accv[3] * inv, 0.f));
    o1.x = f2b(fmaxf(sk[4] + accv[4] * inv, 0.f));
    o1.y = f2b(fmaxf(sk[5] + accv[5] * inv, 0.f));
    o1.z = f2b(fmaxf(sk[6] + accv[6] * inv, 0.f));
    o1.w = f2b(fmaxf(sk[7] + accv[7] * inv, 0.f));
    *reinterpret_cast<ushort4*>(&outb[rbase]) = o0;
    *reinterpret_cast<ushort4*>(&outb[rbase + 4]) = o1;
}

// ---------------- final-layer aggregation (H=1), q bf16, fp32 out ----------------

__global__ __launch_bounds__(256) void aggf_kernel(const unsigned short* __restrict__ q,
                                                   const unsigned short* __restrict__ kb,
                                                   const unsigned short* __restrict__ vb,
                                                   const int* __restrict__ offs, const int* __restrict__ csrc,
                                                   float* __restrict__ out, int N) {
    const int HC = 64;
    int lane = threadIdx.x & 63;
    int node = blockIdx.x * (blockDim.x >> 6) + (threadIdx.x >> 6);
    if (node >= N) return;
    int g = lane >> 4;
    int r = lane & 15;

    unsigned qbase = (unsigned)node * 64u + 4u * r;
    ushort4 q4u = *reinterpret_cast<const ushort4*>(&q[qbase]);
    float q4[4] = {b2f(q4u.x), b2f(q4u.y), b2f(q4u.z), b2f(q4u.w)};

    int e0 = offs[node], e1 = offs[node + 1];
    float m = -3.4e38f, wsum = 0.f;
    float accv[4] = {0.f, 0.f, 0.f, 0.f};

    int nIt = (e1 - e0 + 3) >> 2;
    for (int it = 0; it < nIt; ++it) {
        int s = e0 + it * 4 + g;
        bool valid = s < e1;
        unsigned base = (unsigned)csrc[valid ? s : (e1 - 1)] * 64u + 4u * r;
        ushort4 k4 = *reinterpret_cast<const ushort4*>(&kb[base]);
        float d = q4[0] * b2f(k4.x) + q4[1] * b2f(k4.y) + q4[2] * b2f(k4.z) + q4[3] * b2f(k4.w);
        d += __shfl_xor(d, 1);
        d += __shfl_xor(d, 2);
        d += __shfl_xor(d, 4);
        d += __shfl_xor(d, 8);
        float alpha = valid ? d * 0.125f : -3.4e38f;
        float am = fmaxf(alpha, __shfl_xor(alpha, 16));
        am = fmaxf(am, __shfl_xor(am, 32));
        float mnew = fmaxf(m, am);
        float corr = __expf(m - mnew);
        float ex = __expf(alpha - mnew);
        ushort4 v4 = *reinterpret_cast<const ushort4*>(&vb[base]);
        wsum = wsum * corr + ex;
        accv[0] = accv[0] * corr + ex * b2f(v4.x);
        accv[1] = accv[1] * corr + ex * b2f(v4.y);
        accv[2] = accv[2] * corr + ex * b2f(v4.z);
        accv[3] = accv[3] * corr + ex * b2f(v4.w);
        m = mnew;
    }

    #pragma unroll
    for (int off = 16; off <= 32; off <<= 1) {
        wsum += __shfl_xor(wsum, off);
        #pragma unroll
        for (int j = 0; j < 4; ++j) accv[j] += __shfl_xor(accv[j], off);
    }

    if (g == 0) {
        float inv = (e1 > e0) ? (1.0f / wsum) : 0.f;
        float4 o = *reinterpret_cast<const float4*>(&out[qbase]);
        o.x += accv[0] * inv;
        o.y += accv[1] * inv;
        o.z += accv[2] * inv;
        o.w += accv[3] * inv;
        *reinterpret_cast<float4*>(&out[qbase]) = o;
    }
}

// ---------------- mean pool + MLP head ----------------

__global__ void pool_kernel(const float* __restrict__ hin, float* __restrict__ g, int N) {
    int dim = blockIdx.x;
    float s = 0.f;
    for (int i = threadIdx.x; i < N; i += blockDim.x) s += hin[(size_t)i * 64 + dim];
    __shared__ float red[256];
    red[threadIdx.x] = s;
    __syncthreads();
    for (int d = 128; d >= 1; d >>= 1) {
        if ((int)threadIdx.x < d) red[threadIdx.x] += red[threadIdx.x + d];
        __syncthreads();
    }
    if (threadIdx.x == 0) g[dim] = red[0] / (float)N;
}

__global__ void mlp_kernel(const float* __restrict__ g, const float* __restrict__ Wc1,
                           const float* __restrict__ bc1, const float* __restrict__ Wc2,
                           const float* __restrict__ bc2, float* __restrict__ out) {
    __shared__ float gs[64];
    __shared__ float h1[32];
    int t = threadIdx.x;
    if (t < 64) gs[t] = g[t];
    __syncthreads();
    if (t < 32) {
        float s = bc1[t];
        for (int i = 0; i < 64; ++i) s += gs[i] * Wc1[i * 32 + t];
        h1[t] = fmaxf(s, 0.f);
    }
    __syncthreads();
    if (t < 2) {
        float s = bc2[t];
        for (int i = 0; i < 32; ++i) s += h1[i] * Wc2[i * 2 + t];
        out[t] = s;
    }
}

// ---------------- launch ----------------

extern "C" void kernel_launch(void* const* d_in, const int* in_sizes, int n_in,
                              void* d_out, int out_size, void* d_ws, size_t ws_size,
                              hipStream_t stream) {
    const float* x   = (const float*)d_in[0];
    const int*   ei  = (const int*)d_in[1];
    const float* Wp  = (const float*)d_in[2];
    const float* bp  = (const float*)d_in[3];
    const float* Wq0 = (const float*)d_in[4];
    const float* Wk0 = (const float*)d_in[5];
    const float* Wv0 = (const float*)d_in[6];
    const float* Ws0 = (const float*)d_in[7];
    const float* bq0 = (const float*)d_in[8];
    const float* bk0 = (const float*)d_in[9];
    const float* bv0 = (const float*)d_in[10];
    const float* bs0 = (const float*)d_in[11];
    const float* Wq  = (const float*)d_in[12];
    const float* Wk  = (const float*)d_in[13];
    const float* Wv  = (const float*)d_in[14];
    const float* Ws  = (const float*)d_in[15];
    const float* bq  = (const float*)d_in[16];
    const float* bk  = (const float*)d_in[17];
    const float* bv  = (const float*)d_in[18];
    const float* bs  = (const float*)d_in[19];
    const float* Wqf = (const float*)d_in[20];
    const float* Wkf = (const float*)d_in[21];
    const float* Wvf = (const float*)d_in[22];
    const float* Wsf = (const float*)d_in[23];
    const float* bqf = (const float*)d_in[24];
    const float* bkf = (const float*)d_in[25];
    const float* bvf = (const float*)d_in[26];
    const float* bsf = (const float*)d_in[27];
    const float* Wc1 = (const float*)d_in[28];
    const float* bc1 = (const float*)d_in[29];
    const float* Wc2 = (const float*)d_in[30];
    const float* bc2 = (const float*)d_in[31];

    const int N = in_sizes[0] / 256;
    const int E = in_sizes[1] / 2;
    const int HC = 512;

    size_t NB = (size_t)N * HC;
    const size_t WSMALL = 64 * 256 + 8 * 512 * 64;
    size_t need = 6 * NB * sizeof(unsigned short)
                + (size_t)16 * 512 * 512 * sizeof(unsigned short)
                + WSMALL * sizeof(unsigned short)
                + NB * sizeof(float)
                + (size_t)(2 * N + 1 + E) * sizeof(int)
                + 64 * sizeof(float) + 4096;
    if (ws_size < need) return;

    unsigned short* h0    = (unsigned short*)d_ws;
    unsigned short* h1    = h0 + NB;
    unsigned short* qb16  = h1 + NB;
    unsigned short* kb    = qb16 + NB;
    unsigned short* vb    = kb + NB;
    unsigned short* skipb = vb + NB;
    unsigned short* wt16  = skipb + NB;
    unsigned short* wsm   = wt16 + (size_t)16 * 512 * 512;
    uintptr_t pa = (uintptr_t)(wsm + WSMALL);
    pa = (pa + 255) & ~(uintptr_t)255;
    float* hf32 = (float*)pa;
    int* offs   = (int*)(hf32 + NB);
    int* cursor = offs + (N + 1);
    int* csrc   = cursor + N;
    float* gbuf = (float*)(csrc + E);
    int*   bsum = (int*)(gbuf + 64);
    unsigned short* xb = qb16;  // alias: qb16 free until layer 0 writes it

    int nsb = cdiv(N, 256);

    // --- CSR build (by dst), hierarchical scan ---
    hipMemsetAsync(cursor, 0, sizeof(int) * N, stream);
    count_kernel<<<cdiv(E, 256), 256, 0, stream>>>(ei, cursor, E);
    scan1_kernel<<<nsb, 256, 0, stream>>>(cursor, offs, bsum, N);
    scan2_kernel<<<1, 64, 0, stream>>>(bsum, offs, nsb);
    scan3_kernel<<<nsb, 256, 0, stream>>>(offs, bsum, N);
    hipMemsetAsync(cursor, 0, sizeof(int) * N, stream);
    fill_kernel<<<cdiv(E, 256), 256, 0, stream>>>(ei, offs, cursor, csrc, E);

    // --- weight prep ---
    transpose_b16_kernel<<<dim3(16, 16, 16), dim3(32, 8), 0, stream>>>(Wq, Wk, Wv, Ws, wt16);
    {
        SmallT st;
        unsigned short* wp_t = wsm;
        unsigned short* w0_t = wsm + 64 * 256;
        unsigned short* wf_t = w0_t + 4 * 512 * 64;
        st.src[0] = Wp;  st.dst[0] = wp_t; st.rows[0] = 256; st.cols[0] = 64;
        const float* w0s[4] = {Wq0, Wk0, Wv0, Ws0};
        const float* wfs[4] = {Wqf, Wkf, Wvf, Wsf};
        for (int i = 0; i < 4; ++i) {
            st.src[1 + i] = w0s[i]; st.dst[1 + i] = w0_t + i * 512 * 64;
            st.rows[1 + i] = 64; st.cols[1 + i] = 512;
            st.src[5 + i] = wfs[i]; st.dst[5 + i] = wf_t + i * 64 * 512;
            st.rows[5 + i] = 512; st.cols[5 + i] = 64;
        }
        transpose_small_kernel<<<dim3(32, 9), dim3(32, 8), 0, stream>>>(st);
    }

    // --- input projection: h0 = bf16(x @ Wp + bp)  [N,64] ---
    f2b_kernel<<<1280, 256, 0, stream>>>(x, xb, N * 256 / 4);
    {
        GemmPtrs gp;
        for (int j = 0; j < 4; ++j) {
            gp.B[j] = wsm; gp.bias[j] = bp; gp.C[j] = h0; gp.bf16[j] = 1;
        }
        mfma_flex<<<dim3(cdiv(N, 128), 1), 256, 0, stream>>>(xb, gp, N, 256, 64);
    }

    // --- layer 0: 64 -> 512 (H=8, concat) ---
    {
        GemmPtrs gp;
        unsigned short* w0_t = wsm + 64 * 256;
        gp.B[0] = w0_t + 0 * 512 * 64; gp.bias[0] = bq0; gp.C[0] = qb16;  gp.bf16[0] = 1;
        gp.B[1] = w0_t + 1 * 512 * 64; gp.bias[1] = bk0; gp.C[1] = kb;    gp.bf16[1] = 1;
        gp.B[2] = w0_t + 2 * 512 * 64; gp.bias[2] = bv0; gp.C[2] = vb;    gp.bf16[2] = 1;
        gp.B[3] = w0_t + 3 * 512 * 64; gp.bias[3] = bs0; gp.C[3] = skipb; gp.bf16[3] = 1;
        mfma_flex<<<dim3(cdiv(N, 128), 4 * 8), 256, 0, stream>>>(h0, gp, N, 64, 512);
    }
    agg8_kernel<<<cdiv(N, 4), 256, 0, stream>>>(qb16, kb, vb, skipb, offs, csrc, h1, N);

    // --- layers 1..4: 512 -> 512, fused q/k/v/s MFMA (all-bf16 chain) ---
    unsigned short* hcur = h1;
    unsigned short* hnext = h0;
    int gx = cdiv(N, 128);
    for (int l = 0; l < 4; ++l) {
        GemmPtrs gp;
        gp.B[0] = wt16 + (size_t)(l * 4 + 0) * 512 * 512;
        gp.B[1] = wt16 + (size_t)(l * 4 + 1) * 512 * 512;
        gp.B[2] = wt16 + (size_t)(l * 4 + 2) * 512 * 512;
        gp.B[3] = wt16 + (size_t)(l * 4 + 3) * 512 * 512;
        gp.bias[0] = bq + l * HC;
        gp.bias[1] = bk + l * HC;
        gp.bias[2] = bv + l * HC;
        gp.bias[3] = bs + l * HC;
        gp.C[0] = qb16; gp.C[1] = kb; gp.C[2] = vb; gp.C[3] = skipb;
        gp.bf16[0] = 1; gp.bf16[1] = 1; gp.bf16[2] = 1; gp.bf16[3] = 1;
        mfma_gemm4<<<gx * 16, 256, 0, stream>>>(hcur, gp, N, gx * 16);
        agg8_kernel<<<cdiv(N, 4), 256, 0, stream>>>(qb16, kb, vb, skipb, offs, csrc, hnext, N);
        { unsigned short* t = hcur; hcur = hnext; hnext = t; }
    }

    // --- final layer: 512 -> 64 (H=1, no concat, no relu) ---
    {
        GemmPtrs gp;
        unsigned short* wf_t = wsm + 64 * 256 + 4 * 512 * 64;
        gp.B[0] = wf_t + 0 * 64 * 512; gp.bias[0] = bqf; gp.C[0] = qb16; gp.bf16[0] = 1;
        gp.B[1] = wf_t + 1 * 64 * 512; gp.bias[1] = bkf; gp.C[1] = kb;   gp.bf16[1] = 1;
        gp.B[2] = wf_t + 2 * 64 * 512; gp.bias[2] = bvf; gp.C[2] = vb;   gp.bf16[2] = 1;
        gp.B[3] = wf_t + 3 * 64 * 512; gp.bias[3] = bsf; gp.C[3] = hf32; gp.bf16[3] = 0;
        mfma_flex<<<dim3(cdiv(N, 128), 4), 256, 0, stream>>>(hcur, gp, N, 512, 64);
    }
    aggf_kernel<<<cdiv(N, 4), 256, 0, stream>>>(qb16, kb, vb, offs, csrc, hf32, N);

    // --- mean pool + MLP ---
    pool_kernel<<<64, 256, 0, stream>>>(hf32, gbuf, N);
    mlp_kernel<<<1, 64, 0, stream>>>(gbuf, Wc1, bc1, Wc2, bc2, (float*)d_out);
}

// Round 17
// 561.283 us; speedup vs baseline: 1.0203x; 1.0106x over previous
//
#include <hip/hip_runtime.h>
#include <hip/hip_bf16.h>
#include <cstddef>
#include <cstdint>

static inline int cdiv(int a, int b) { return (a + b - 1) / b; }

typedef short short8v __attribute__((ext_vector_type(8)));
typedef float float4v __attribute__((ext_vector_type(4)));

__device__ inline unsigned short f2b(float f) {
    union { float f; unsigned u; } x; x.f = f;
    unsigned u = x.u;
    return (unsigned short)((u + 0x7fff + ((u >> 16) & 1)) >> 16);
}

__device__ inline float lo2f(unsigned u) { union { unsigned x; float f; } c; c.x = u << 16; return c.f; }
__device__ inline float hi2f(unsigned u) { union { unsigned x; float f; } c; c.x = u & 0xffff0000u; return c.f; }
__device__ inline float b2f(unsigned short b) {
    union { unsigned u; float f; } x; x.u = ((unsigned)b) << 16;
    return x.f;
}

__device__ __forceinline__ void u4tof8(uint4 u, float* f) {
    f[0] = lo2f(u.x); f[1] = hi2f(u.x); f[2] = lo2f(u.y); f[3] = hi2f(u.y);
    f[4] = lo2f(u.z); f[5] = hi2f(u.z); f[6] = lo2f(u.w); f[7] = hi2f(u.w);
}

// async global -> LDS, 16 bytes per lane (wave-uniform LDS base + lane*16)
__device__ __forceinline__ void gload_lds16(const unsigned short* g, unsigned short* lds) {
    __builtin_amdgcn_global_load_lds(
        (const __attribute__((address_space(1))) unsigned int*)g,
        (__attribute__((address_space(3))) unsigned int*)lds, 16, 0, 0);
}

// ---------------- CSR build ----------------

__global__ void count_kernel(const int* __restrict__ ei, int* __restrict__ indeg, int E) {
    int e = blockIdx.x * blockDim.x + threadIdx.x;
    if (e < E) atomicAdd(&indeg[ei[E + e]], 1);
}

__global__ void scan1_kernel(const int* __restrict__ deg, int* __restrict__ offs,
                             int* __restrict__ bsum, int n) {
    __shared__ int tmp[256];
    int i = blockIdx.x * 256 + threadIdx.x;
    int v = (i < n) ? deg[i] : 0;
    tmp[threadIdx.x] = v;
    __syncthreads();
    for (int d = 1; d < 256; d <<= 1) {
        int a = (threadIdx.x >= (unsigned)d) ? tmp[threadIdx.x - d] : 0;
        __syncthreads();
        tmp[threadIdx.x] += a;
        __syncthreads();
    }
    if (i < n) offs[i + 1] = tmp[threadIdx.x];
    if (threadIdx.x == 255) bsum[blockIdx.x] = tmp[255];
}

__global__ void scan2_kernel(int* __restrict__ bsum, int* __restrict__ offs, int nb) {
    if (threadIdx.x == 0) {
        offs[0] = 0;
        int base = 0;
        for (int b = 0; b < nb; ++b) { int t = bsum[b]; bsum[b] = base; base += t; }
    }
}

__global__ void scan3_kernel(int* __restrict__ offs, const int* __restrict__ bsum, int n) {
    int i = blockIdx.x * 256 + threadIdx.x;
    if (i < n) offs[i + 1] += bsum[blockIdx.x];
}

__global__ void fill_kernel(const int* __restrict__ ei, const int* __restrict__ offs,
                            int* __restrict__ cursor, int* __restrict__ csrc, int E) {
    int e = blockIdx.x * blockDim.x + threadIdx.x;
    if (e < E) {
        int d = ei[E + e];
        int s = ei[e];
        int pos = atomicAdd(&cursor[d], 1);
        csrc[offs[d] + pos] = s;
    }
}

// ---------------- fp32 -> bf16 ----------------

__global__ void f2b_kernel(const float* __restrict__ in, unsigned short* __restrict__ out, int n4) {
    int stride = gridDim.x * blockDim.x;
    for (int i = blockIdx.x * blockDim.x + threadIdx.x; i < n4; i += stride) {
        float4 v = reinterpret_cast<const float4*>(in)[i];
        ushort4 o;
        o.x = f2b(v.x); o.y = f2b(v.y); o.z = f2b(v.z); o.w = f2b(v.w);
        reinterpret_cast<ushort4*>(out)[i] = o;
    }
}

// Transpose+convert 16 big weights [512][512] fp32 -> bf16 [Nc][K].
__global__ void transpose_b16_kernel(const float* __restrict__ Wq, const float* __restrict__ Wk,
                                     const float* __restrict__ Wv, const float* __restrict__ Ws,
                                     unsigned short* __restrict__ out) {
    const int K = 512, Nc = 512;
    int z = blockIdx.z;
    int which = z & 3;
    const float* W = (which == 0) ? Wq : (which == 1) ? Wk : (which == 2) ? Wv : Ws;
    W += (size_t)(z >> 2) * K * Nc;
    unsigned short* Wt = out + (size_t)z * K * Nc;
    __shared__ float t[32][33];
    int k0 = blockIdx.x * 32, c0 = blockIdx.y * 32;
    int tx = threadIdx.x, ty = threadIdx.y;
    #pragma unroll
    for (int i = 0; i < 32; i += 8) t[ty + i][tx] = W[(size_t)(k0 + ty + i) * Nc + c0 + tx];
    __syncthreads();
    #pragma unroll
    for (int i = 0; i < 32; i += 8) Wt[(size_t)(c0 + ty + i) * K + k0 + tx] = f2b(t[tx][ty + i]);
}

// Batched transpose of 9 small weights.
struct SmallT {
    const float* src[9];
    unsigned short* dst[9];
    int rows[9];
    int cols[9];
};

__global__ void transpose_small_kernel(SmallT p) {
    int mat = blockIdx.y;
    int rows = p.rows[mat], cols = p.cols[mat];
    int tilesC = cols >> 5;
    int tiles = (rows >> 5) * tilesC;
    if ((int)blockIdx.x >= tiles) return;
    int tr = blockIdx.x / tilesC, tc = blockIdx.x % tilesC;
    const float* src = p.src[mat];
    unsigned short* dst = p.dst[mat];
    __shared__ float t[32][33];
    int r0 = tr * 32, c0 = tc * 32;
    int tx = threadIdx.x, ty = threadIdx.y;
    #pragma unroll
    for (int i = 0; i < 32; i += 8) t[ty + i][tx] = src[(size_t)(r0 + ty + i) * cols + c0 + tx];
    __syncthreads();
    #pragma unroll
    for (int i = 0; i < 32; i += 8) dst[(size_t)(c0 + ty + i) * rows + r0 + tx] = f2b(t[tx][ty + i]);
}

// ---------------- fused bf16 MFMA GEMM (512x512), 3-deep counted-vmcnt pipeline + T5 ----------------
// BK=32, 3 LDS buffers. Per iter: vmcnt(8) (wait ONLY current tile; 2 tiles stay in flight)
// -> raw s_barrier -> ds_read + setprio(1) MFMA setprio(0) -> raw s_barrier -> issue tile i+3.
// Never drains vmcnt to 0 in steady state (T4). T2 slot-swizzle (conflicts = 0). T5 setprio:
// counted-vmcnt phase split gives waves different roles -> scheduler can favor MFMA waves.

struct GemmPtrs {
    const unsigned short* B[4];
    const float* bias[4];
    void* C[4];
    int bf16[4];
};

__global__ __launch_bounds__(256) void mfma_gemm4(const unsigned short* __restrict__ A,
                                                  GemmPtrs p, int M, int nb) {
    __shared__ unsigned short As[3][128 * 32];
    __shared__ unsigned short Bs[3][128 * 32];
    int i = blockIdx.x;
    int wk = (nb & 7) ? i : ((i & 7) * (nb >> 3) + (i >> 3));  // T1 XCD swizzle
    int xt = wk >> 4, yt = wk & 15;
    int row0 = xt * 128;
    int wsel = yt >> 2;
    int col0 = (yt & 3) * 128;
    const unsigned short* Bt = p.B[wsel];

    int tid = threadIdx.x;
    int lane = tid & 63;
    int w = tid >> 6;
    int wr = w >> 1, wc = w & 1;
    float4v acc[4][4] = {};

    int c0i = w * 2;
    int srow0 = c0i * 16 + (lane >> 2);
    int srow1 = srow0 + 16;
    int sslot0 = (lane & 3) ^ ((srow0 >> 1) & 3);   // T2 pre-swizzled 16B slot
    int sslot1 = (lane & 3) ^ ((srow1 >> 1) & 3);

    const unsigned short* Ag0 = A + (size_t)(row0 + srow0) * 512 + sslot0 * 8;
    const unsigned short* Ag1 = A + (size_t)(row0 + srow1) * 512 + sslot1 * 8;
    const unsigned short* Bg0 = Bt + (size_t)(col0 + srow0) * 512 + sslot0 * 8;
    const unsigned short* Bg1 = Bt + (size_t)(col0 + srow1) * 512 + sslot1 * 8;

    // prologue: prefetch tiles 0..2 (12 loads in flight per thread)
    #pragma unroll
    for (int t = 0; t < 3; ++t) {
        gload_lds16(Ag0 + t * 32, &As[t][c0i * 512]);
        gload_lds16(Ag1 + t * 32, &As[t][(c0i + 1) * 512]);
        gload_lds16(Bg0 + t * 32, &Bs[t][c0i * 512]);
        gload_lds16(Bg1 + t * 32, &Bs[t][(c0i + 1) * 512]);
    }

    int r16 = lane & 15;
    int ks = lane >> 4;

    #pragma unroll
    for (int kt = 0; kt < 16; ++kt) {
        if (kt <= 13)      { asm volatile("s_waitcnt vmcnt(8)" ::: "memory"); }
        else if (kt == 14) { asm volatile("s_waitcnt vmcnt(4)" ::: "memory"); }
        else               { asm volatile("s_waitcnt vmcnt(0)" ::: "memory"); }
        __builtin_amdgcn_sched_barrier(0);
        __builtin_amdgcn_s_barrier();        // all waves' tile-kt loads landed
        int buf = kt % 3;
        short8v af[4], bf[4];
        #pragma unroll
        for (int mi = 0; mi < 4; ++mi) {
            int row = wr * 64 + mi * 16 + r16;
            int slot = ks ^ ((row >> 1) & 3);
            af[mi] = *reinterpret_cast<const short8v*>(&As[buf][row * 32 + slot * 8]);
        }
        #pragma unroll
        for (int nj = 0; nj < 4; ++nj) {
            int row = wc * 64 + nj * 16 + r16;
            int slot = ks ^ ((row >> 1) & 3);
            bf[nj] = *reinterpret_cast<const short8v*>(&Bs[buf][row * 32 + slot * 8]);
        }
        __builtin_amdgcn_s_setprio(1);       // T5: favor MFMA-entering waves
        #pragma unroll
        for (int mi = 0; mi < 4; ++mi)
            #pragma unroll
            for (int nj = 0; nj < 4; ++nj)
                acc[mi][nj] = __builtin_amdgcn_mfma_f32_16x16x32_bf16(af[mi], bf[nj], acc[mi][nj], 0, 0, 0);
        __builtin_amdgcn_s_setprio(0);
        __builtin_amdgcn_s_barrier();        // all reads of buf done -> safe to overwrite
        if (kt <= 12) {
            int nk = (kt + 3) * 32;
            gload_lds16(Ag0 + nk, &As[buf][c0i * 512]);
            gload_lds16(Ag1 + nk, &As[buf][(c0i + 1) * 512]);
            gload_lds16(Bg0 + nk, &Bs[buf][c0i * 512]);
            gload_lds16(Bg1 + nk, &Bs[buf][(c0i + 1) * 512]);
        }
    }

    const float* bias = p.bias[wsel];
    int outbf = p.bf16[wsel];
    float* Cf = (float*)p.C[wsel];
    unsigned short* Cb = (unsigned short*)p.C[wsel];
    int crow_base = row0 + wr * 64 + (lane >> 4) * 4;
    int ccol_base = col0 + wc * 64 + (lane & 15);
    #pragma unroll
    for (int mi = 0; mi < 4; ++mi) {
        #pragma unroll
        for (int r = 0; r < 4; ++r) {
            int grow = crow_base + mi * 16 + r;
            if (grow >= M) continue;
            #pragma unroll
            for (int nj = 0; nj < 4; ++nj) {
                int gcol = ccol_base + nj * 16;
                float val = acc[mi][nj][r] + bias[gcol];
                if (outbf) Cb[(size_t)grow * 512 + gcol] = f2b(val);
                else       Cf[(size_t)grow * 512 + gcol] = val;
            }
        }
    }
}

// ---------------- flexible MFMA GEMM: BM=128, BN=64, BK=32, runtime K/N ----------------

__global__ __launch_bounds__(256) void mfma_flex(const unsigned short* __restrict__ A,
                                                 GemmPtrs p, int M, int K, int Nc) {
    __shared__ unsigned short As[128][40];
    __shared__ unsigned short Bs[64][40];
    int tid = threadIdx.x;
    int lane = tid & 63;
    int w = tid >> 6;
    int row0 = blockIdx.x * 128;
    int nb = Nc >> 6;
    int wsel = blockIdx.y / nb;
    int col0 = (blockIdx.y % nb) * 64;
    const unsigned short* Bt = p.B[wsel];

    float4v acc[2][4] = {};

    int ra = tid >> 1;
    int ca = (tid & 1) * 16;
    int rb = tid >> 2;
    int cb = (tid & 3) * 8;

    for (int k0 = 0; k0 < K; k0 += 32) {
        {
            int grow = row0 + ra;
            uint4 a0 = make_uint4(0u, 0u, 0u, 0u), a1 = make_uint4(0u, 0u, 0u, 0u);
            if (grow < M) {
                a0 = *reinterpret_cast<const uint4*>(&A[(size_t)grow * K + k0 + ca]);
                a1 = *reinterpret_cast<const uint4*>(&A[(size_t)grow * K + k0 + ca + 8]);
            }
            *reinterpret_cast<uint4*>(&As[ra][ca]) = a0;
            *reinterpret_cast<uint4*>(&As[ra][ca + 8]) = a1;
            uint4 bv = *reinterpret_cast<const uint4*>(&Bt[(size_t)(col0 + rb) * K + k0 + cb]);
            *reinterpret_cast<uint4*>(&Bs[rb][cb]) = bv;
        }
        __syncthreads();
        short8v af[2], bf[4];
        int r16 = lane & 15;
        int kc = (lane >> 4) * 8;
        #pragma unroll
        for (int mi = 0; mi < 2; ++mi)
            af[mi] = *reinterpret_cast<const short8v*>(&As[w * 32 + mi * 16 + r16][kc]);
        #pragma unroll
        for (int nj = 0; nj < 4; ++nj)
            bf[nj] = *reinterpret_cast<const short8v*>(&Bs[nj * 16 + r16][kc]);
        #pragma unroll
        for (int mi = 0; mi < 2; ++mi)
            #pragma unroll
            for (int nj = 0; nj < 4; ++nj)
                acc[mi][nj] = __builtin_amdgcn_mfma_f32_16x16x32_bf16(af[mi], bf[nj], acc[mi][nj], 0, 0, 0);
        __syncthreads();
    }

    const float* bias = p.bias[wsel];
    int outbf = p.bf16[wsel];
    float* Cf = (float*)p.C[wsel];
    unsigned short* Cb = (unsigned short*)p.C[wsel];
    int crow_base = row0 + w * 32 + (lane >> 4) * 4;
    int ccol_base = col0 + (lane & 15);
    #pragma unroll
    for (int mi = 0; mi < 2; ++mi) {
        #pragma unroll
        for (int r = 0; r < 4; ++r) {
            int grow = crow_base + mi * 16 + r;
            if (grow >= M) continue;
            #pragma unroll
            for (int nj = 0; nj < 4; ++nj) {
                int gcol = ccol_base + nj * 16;
                float val = acc[mi][nj][r] + bias[gcol];
                if (outbf) Cb[(size_t)grow * Nc + gcol] = f2b(val);
                else       Cf[(size_t)grow * Nc + gcol] = val;
            }
        }
    }
}

// ---------------- head-combined edge aggregation (H=8), all-bf16 I/O ----------------
// One wave per node; 8-lane group per head. exp2-domain softmax + defer-max (T13)
// + 32-bit offsets + 4-edge unroll (8 gather loads in flight per wave).

__global__ __launch_bounds__(256) void agg8_kernel(const unsigned short* __restrict__ q,
                                                   const unsigned short* __restrict__ kb,
                                                   const unsigned short* __restrict__ vb,
                                                   const unsigned short* __restrict__ skip,
                                                   const int* __restrict__ offs, const int* __restrict__ csrc,
                                                   unsigned short* __restrict__ outb, int N) {
    int lane = threadIdx.x & 63;
    int node = blockIdx.x * (blockDim.x >> 6) + (threadIdx.x >> 6);
    if (node >= N) return;

    unsigned co = (unsigned)lane * 8u;
    unsigned rbase = (unsigned)node * 512u + co;
    float qv[8];
    u4tof8(*reinterpret_cast<const uint4*>(&q[rbase]), qv);

    int e0 = offs[node], e1 = offs[node + 1];
    float m = -1e30f, wsum = 0.f;
    float accv[8] = {};
    const float SC = 0.125f * 1.4426950408889634f;

    int s = e0;
    for (; s + 4 <= e1; s += 4) {
        unsigned b0 = (unsigned)csrc[s] * 512u + co;
        unsigned b1 = (unsigned)csrc[s + 1] * 512u + co;
        unsigned b2 = (unsigned)csrc[s + 2] * 512u + co;
        unsigned b3 = (unsigned)csrc[s + 3] * 512u + co;
        uint4 k0 = *reinterpret_cast<const uint4*>(&kb[b0]);
        uint4 k1 = *reinterpret_cast<const uint4*>(&kb[b1]);
        uint4 k2 = *reinterpret_cast<const uint4*>(&kb[b2]);
        uint4 k3 = *reinterpret_cast<const uint4*>(&kb[b3]);
        uint4 v0 = *reinterpret_cast<const uint4*>(&vb[b0]);
        uint4 v1 = *reinterpret_cast<const uint4*>(&vb[b1]);
        uint4 v2 = *reinterpret_cast<const uint4*>(&vb[b2]);
        uint4 v3 = *reinterpret_cast<const uint4*>(&vb[b3]);
        float kk0[8], kk1[8], kk2[8], kk3[8];
        u4tof8(k0, kk0); u4tof8(k1, kk1); u4tof8(k2, kk2); u4tof8(k3, kk3);
        float d0 = 0.f, d1 = 0.f, d2 = 0.f, d3 = 0.f;
        #pragma unroll
        for (int j = 0; j < 8; ++j) {
            d0 += qv[j] * kk0[j]; d1 += qv[j] * kk1[j];
            d2 += qv[j] * kk2[j]; d3 += qv[j] * kk3[j];
        }
        d0 += __shfl_xor(d0, 1); d1 += __shfl_xor(d1, 1); d2 += __shfl_xor(d2, 1); d3 += __shfl_xor(d3, 1);
        d0 += __shfl_xor(d0, 2); d1 += __shfl_xor(d1, 2); d2 += __shfl_xor(d2, 2); d3 += __shfl_xor(d3, 2);
        d0 += __shfl_xor(d0, 4); d1 += __shfl_xor(d1, 4); d2 += __shfl_xor(d2, 4); d3 += __shfl_xor(d3, 4);
        float a0 = d0 * SC, a1 = d1 * SC, a2 = d2 * SC, a3 = d3 * SC;
        float am = fmaxf(fmaxf(a0, a1), fmaxf(a2, a3));
        if (__any(am > m + 8.f)) {
            float mnew = fmaxf(m, am);
            float corr = exp2f(m - mnew);
            wsum *= corr;
            #pragma unroll
            for (int j = 0; j < 8; ++j) accv[j] *= corr;
            m = mnew;
        }
        float x0 = exp2f(a0 - m);
        float x1 = exp2f(a1 - m);
        float x2 = exp2f(a2 - m);
        float x3 = exp2f(a3 - m);
        wsum += (x0 + x1) + (x2 + x3);
        float vv0[8], vv1[8], vv2[8], vv3[8];
        u4tof8(v0, vv0); u4tof8(v1, vv1); u4tof8(v2, vv2); u4tof8(v3, vv3);
        #pragma unroll
        for (int j = 0; j < 8; ++j)
            accv[j] += (x0 * vv0[j] + x1 * vv1[j]) + (x2 * vv2[j] + x3 * vv3[j]);
    }
    for (; s < e1; ++s) {
        unsigned b0 = (unsigned)csrc[s] * 512u + co;
        float kk0[8], vv0[8];
        u4tof8(*reinterpret_cast<const uint4*>(&kb[b0]), kk0);
        u4tof8(*reinterpret_cast<const uint4*>(&vb[b0]), vv0);
        float d0 = 0.f;
        #pragma unroll
        for (int j = 0; j < 8; ++j) d0 += qv[j] * kk0[j];
        d0 += __shfl_xor(d0, 1);
        d0 += __shfl_xor(d0, 2);
        d0 += __shfl_xor(d0, 4);
        float a0 = d0 * SC;
        if (__any(a0 > m + 8.f)) {
            float mnew = fmaxf(m, a0);
            float corr = exp2f(m - mnew);
            wsum *= corr;
            #pragma unroll
            for (int j = 0; j < 8; ++j) accv[j] *= corr;
            m = mnew;
        }
        float x0 = exp2f(a0 - m);
        wsum += x0;
        #pragma unroll
        for (int j = 0; j < 8; ++j) accv[j] += x0 * vv0[j];
    }

    float inv = (e1 > e0) ? (1.0f / wsum) : 0.f;
    float sk[8];
    u4tof8(*reinterpret_cast<const uint4*>(&skip[rbase]), sk);
    ushort4 o0, o1;
    o0.x = f2b(fmaxf(sk[0] + accv[0] * inv, 0.f));
    o0.y = f2b(fmaxf(sk[1] + accv[1] * inv, 0.f));
    o0.z = f2b(fmaxf(sk[2] + accv[2] * inv, 0.f));
    o0.w = f2b(fmaxf(sk[3] + accv[3] * inv, 0.f));
    o1.x = f2b(fmaxf(sk[4] + accv[4] * inv, 0.f));
    o1.y = f2b(fmaxf(sk[5] + accv[5] * inv, 0.f));
    o1.z = f2b(fmaxf(sk[6] + accv[6] * inv, 0.f));
    o1.w = f2b(fmaxf(sk[7] + accv[7] * inv, 0.f));
    *reinterpret_cast<ushort4*>(&outb[rbase]) = o0;
    *reinterpret_cast<ushort4*>(&outb[rbase + 4]) = o1;
}

// ---------------- final-layer aggregation (H=1), q bf16, fp32 out ----------------

__global__ __launch_bounds__(256) void aggf_kernel(const unsigned short* __restrict__ q,
                                                   const unsigned short* __restrict__ kb,
                                                   const unsigned short* __restrict__ vb,
                                                   const int* __restrict__ offs, const int* __restrict__ csrc,
                                                   float* __restrict__ out, int N) {
    const int HC = 64;
    int lane = threadIdx.x & 63;
    int node = blockIdx.x * (blockDim.x >> 6) + (threadIdx.x >> 6);
    if (node >= N) return;
    int g = lane >> 4;
    int r = lane & 15;

    unsigned qbase = (unsigned)node * 64u + 4u * r;
    ushort4 q4u = *reinterpret_cast<const ushort4*>(&q[qbase]);
    float q4[4] = {b2f(q4u.x), b2f(q4u.y), b2f(q4u.z), b2f(q4u.w)};

    int e0 = offs[node], e1 = offs[node + 1];
    float m = -3.4e38f, wsum = 0.f;
    float accv[4] = {0.f, 0.f, 0.f, 0.f};

    int nIt = (e1 - e0 + 3) >> 2;
    for (int it = 0; it < nIt; ++it) {
        int s = e0 + it * 4 + g;
        bool valid = s < e1;
        unsigned base = (unsigned)csrc[valid ? s : (e1 - 1)] * 64u + 4u * r;
        ushort4 k4 = *reinterpret_cast<const ushort4*>(&kb[base]);
        float d = q4[0] * b2f(k4.x) + q4[1] * b2f(k4.y) + q4[2] * b2f(k4.z) + q4[3] * b2f(k4.w);
        d += __shfl_xor(d, 1);
        d += __shfl_xor(d, 2);
        d += __shfl_xor(d, 4);
        d += __shfl_xor(d, 8);
        float alpha = valid ? d * 0.125f : -3.4e38f;
        float am = fmaxf(alpha, __shfl_xor(alpha, 16));
        am = fmaxf(am, __shfl_xor(am, 32));
        float mnew = fmaxf(m, am);
        float corr = __expf(m - mnew);
        float ex = __expf(alpha - mnew);
        ushort4 v4 = *reinterpret_cast<const ushort4*>(&vb[base]);
        wsum = wsum * corr + ex;
        accv[0] = accv[0] * corr + ex * b2f(v4.x);
        accv[1] = accv[1] * corr + ex * b2f(v4.y);
        accv[2] = accv[2] * corr + ex * b2f(v4.z);
        accv[3] = accv[3] * corr + ex * b2f(v4.w);
        m = mnew;
    }

    #pragma unroll
    for (int off = 16; off <= 32; off <<= 1) {
        wsum += __shfl_xor(wsum, off);
        #pragma unroll
        for (int j = 0; j < 4; ++j) accv[j] += __shfl_xor(accv[j], off);
    }

    if (g == 0) {
        float inv = (e1 > e0) ? (1.0f / wsum) : 0.f;
        float4 o = *reinterpret_cast<const float4*>(&out[qbase]);
        o.x += accv[0] * inv;
        o.y += accv[1] * inv;
        o.z += accv[2] * inv;
        o.w += accv[3] * inv;
        *reinterpret_cast<float4*>(&out[qbase]) = o;
    }
}

// ---------------- mean pool + MLP head ----------------

__global__ void pool_kernel(const float* __restrict__ hin, float* __restrict__ g, int N) {
    int dim = blockIdx.x;
    float s = 0.f;
    for (int i = threadIdx.x; i < N; i += blockDim.x) s += hin[(size_t)i * 64 + dim];
    __shared__ float red[256];
    red[threadIdx.x] = s;
    __syncthreads();
    for (int d = 128; d >= 1; d >>= 1) {
        if ((int)threadIdx.x < d) red[threadIdx.x] += red[threadIdx.x + d];
        __syncthreads();
    }
    if (threadIdx.x == 0) g[dim] = red[0] / (float)N;
}

__global__ void mlp_kernel(const float* __restrict__ g, const float* __restrict__ Wc1,
                           const float* __restrict__ bc1, const float* __restrict__ Wc2,
                           const float* __restrict__ bc2, float* __restrict__ out) {
    __shared__ float gs[64];
    __shared__ float h1[32];
    int t = threadIdx.x;
    if (t < 64) gs[t] = g[t];
    __syncthreads();
    if (t < 32) {
        float s = bc1[t];
        for (int i = 0; i < 64; ++i) s += gs[i] * Wc1[i * 32 + t];
        h1[t] = fmaxf(s, 0.f);
    }
    __syncthreads();
    if (t < 2) {
        float s = bc2[t];
        for (int i = 0; i < 32; ++i) s += h1[i] * Wc2[i * 2 + t];
        out[t] = s;
    }
}

// ---------------- launch ----------------

extern "C" void kernel_launch(void* const* d_in, const int* in_sizes, int n_in,
                              void* d_out, int out_size, void* d_ws, size_t ws_size,
                              hipStream_t stream) {
    const float* x   = (const float*)d_in[0];
    const int*   ei  = (const int*)d_in[1];
    const float* Wp  = (const float*)d_in[2];
    const float* bp  = (const float*)d_in[3];
    const float* Wq0 = (const float*)d_in[4];
    const float* Wk0 = (const float*)d_in[5];
    const float* Wv0 = (const float*)d_in[6];
    const float* Ws0 = (const float*)d_in[7];
    const float* bq0 = (const float*)d_in[8];
    const float* bk0 = (const float*)d_in[9];
    const float* bv0 = (const float*)d_in[10];
    const float* bs0 = (const float*)d_in[11];
    const float* Wq  = (const float*)d_in[12];
    const float* Wk  = (const float*)d_in[13];
    const float* Wv  = (const float*)d_in[14];
    const float* Ws  = (const float*)d_in[15];
    const float* bq  = (const float*)d_in[16];
    const float* bk  = (const float*)d_in[17];
    const float* bv  = (const float*)d_in[18];
    const float* bs  = (const float*)d_in[19];
    const float* Wqf = (const float*)d_in[20];
    const float* Wkf = (const float*)d_in[21];
    const float* Wvf = (const float*)d_in[22];
    const float* Wsf = (const float*)d_in[23];
    const float* bqf = (const float*)d_in[24];
    const float* bkf = (const float*)d_in[25];
    const float* bvf = (const float*)d_in[26];
    const float* bsf = (const float*)d_in[27];
    const float* Wc1 = (const float*)d_in[28];
    const float* bc1 = (const float*)d_in[29];
    const float* Wc2 = (const float*)d_in[30];
    const float* bc2 = (const float*)d_in[31];

    const int N = in_sizes[0] / 256;
    const int E = in_sizes[1] / 2;
    const int HC = 512;

    size_t NB = (size_t)N * HC;
    const size_t WSMALL = 64 * 256 + 8 * 512 * 64;
    size_t need = 6 * NB * sizeof(unsigned short)
                + (size_t)16 * 512 * 512 * sizeof(unsigned short)
                + WSMALL * sizeof(unsigned short)
                + NB * sizeof(float)
                + (size_t)(2 * N + 1 + E) * sizeof(int)
                + 64 * sizeof(float) + 4096;
    if (ws_size < need) return;

    unsigned short* h0    = (unsigned short*)d_ws;
    unsigned short* h1    = h0 + NB;
    unsigned short* qb16  = h1 + NB;
    unsigned short* kb    = qb16 + NB;
    unsigned short* vb    = kb + NB;
    unsigned short* skipb = vb + NB;
    unsigned short* wt16  = skipb + NB;
    unsigned short* wsm   = wt16 + (size_t)16 * 512 * 512;
    uintptr_t pa = (uintptr_t)(wsm + WSMALL);
    pa = (pa + 255) & ~(uintptr_t)255;
    float* hf32 = (float*)pa;
    int* offs   = (int*)(hf32 + NB);
    int* cursor = offs + (N + 1);
    int* csrc   = cursor + N;
    float* gbuf = (float*)(csrc + E);
    int*   bsum = (int*)(gbuf + 64);
    unsigned short* xb = qb16;  // alias: qb16 free until layer 0 writes it

    int nsb = cdiv(N, 256);

    // --- CSR build (by dst), hierarchical scan ---
    hipMemsetAsync(cursor, 0, sizeof(int) * N, stream);
    count_kernel<<<cdiv(E, 256), 256, 0, stream>>>(ei, cursor, E);
    scan1_kernel<<<nsb, 256, 0, stream>>>(cursor, offs, bsum, N);
    scan2_kernel<<<1, 64, 0, stream>>>(bsum, offs, nsb);
    scan3_kernel<<<nsb, 256, 0, stream>>>(offs, bsum, N);
    hipMemsetAsync(cursor, 0, sizeof(int) * N, stream);
    fill_kernel<<<cdiv(E, 256), 256, 0, stream>>>(ei, offs, cursor, csrc, E);

    // --- weight prep ---
    transpose_b16_kernel<<<dim3(16, 16, 16), dim3(32, 8), 0, stream>>>(Wq, Wk, Wv, Ws, wt16);
    {
        SmallT st;
        unsigned short* wp_t = wsm;
        unsigned short* w0_t = wsm + 64 * 256;
        unsigned short* wf_t = w0_t + 4 * 512 * 64;
        st.src[0] = Wp;  st.dst[0] = wp_t; st.rows[0] = 256; st.cols[0] = 64;
        const float* w0s[4] = {Wq0, Wk0, Wv0, Ws0};
        const float* wfs[4] = {Wqf, Wkf, Wvf, Wsf};
        for (int i = 0; i < 4; ++i) {
            st.src[1 + i] = w0s[i]; st.dst[1 + i] = w0_t + i * 512 * 64;
            st.rows[1 + i] = 64; st.cols[1 + i] = 512;
            st.src[5 + i] = wfs[i]; st.dst[5 + i] = wf_t + i * 64 * 512;
            st.rows[5 + i] = 512; st.cols[5 + i] = 64;
        }
        transpose_small_kernel<<<dim3(32, 9), dim3(32, 8), 0, stream>>>(st);
    }

    // --- input projection: h0 = bf16(x @ Wp + bp)  [N,64] ---
    f2b_kernel<<<1280, 256, 0, stream>>>(x, xb, N * 256 / 4);
    {
        GemmPtrs gp;
        for (int j = 0; j < 4; ++j) {
            gp.B[j] = wsm; gp.bias[j] = bp; gp.C[j] = h0; gp.bf16[j] = 1;
        }
        mfma_flex<<<dim3(cdiv(N, 128), 1), 256, 0, stream>>>(xb, gp, N, 256, 64);
    }

    // --- layer 0: 64 -> 512 (H=8, concat) ---
    {
        GemmPtrs gp;
        unsigned short* w0_t = wsm + 64 * 256;
        gp.B[0] = w0_t + 0 * 512 * 64; gp.bias[0] = bq0; gp.C[0] = qb16;  gp.bf16[0] = 1;
        gp.B[1] = w0_t + 1 * 512 * 64; gp.bias[1] = bk0; gp.C[1] = kb;    gp.bf16[1] = 1;
        gp.B[2] = w0_t + 2 * 512 * 64; gp.bias[2] = bv0; gp.C[2] = vb;    gp.bf16[2] = 1;
        gp.B[3] = w0_t + 3 * 512 * 64; gp.bias[3] = bs0; gp.C[3] = skipb; gp.bf16[3] = 1;
        mfma_flex<<<dim3(cdiv(N, 128), 4 * 8), 256, 0, stream>>>(h0, gp, N, 64, 512);
    }
    agg8_kernel<<<cdiv(N, 4), 256, 0, stream>>>(qb16, kb, vb, skipb, offs, csrc, h1, N);

    // --- layers 1..4: 512 -> 512, fused q/k/v/s MFMA (all-bf16 chain) ---
    unsigned short* hcur = h1;
    unsigned short* hnext = h0;
    int gx = cdiv(N, 128);
    for (int l = 0; l < 4; ++l) {
        GemmPtrs gp;
        gp.B[0] = wt16 + (size_t)(l * 4 + 0) * 512 * 512;
        gp.B[1] = wt16 + (size_t)(l * 4 + 1) * 512 * 512;
        gp.B[2] = wt16 + (size_t)(l * 4 + 2) * 512 * 512;
        gp.B[3] = wt16 + (size_t)(l * 4 + 3) * 512 * 512;
        gp.bias[0] = bq + l * HC;
        gp.bias[1] = bk + l * HC;
        gp.bias[2] = bv + l * HC;
        gp.bias[3] = bs + l * HC;
        gp.C[0] = qb16; gp.C[1] = kb; gp.C[2] = vb; gp.C[3] = skipb;
        gp.bf16[0] = 1; gp.bf16[1] = 1; gp.bf16[2] = 1; gp.bf16[3] = 1;
        mfma_gemm4<<<gx * 16, 256, 0, stream>>>(hcur, gp, N, gx * 16);
        agg8_kernel<<<cdiv(N, 4), 256, 0, stream>>>(qb16, kb, vb, skipb, offs, csrc, hnext, N);
        { unsigned short* t = hcur; hcur = hnext; hnext = t; }
    }

    // --- final layer: 512 -> 64 (H=1, no concat, no relu) ---
    {
        GemmPtrs gp;
        unsigned short* wf_t = wsm + 64 * 256 + 4 * 512 * 64;
        gp.B[0] = wf_t + 0 * 64 * 512; gp.bias[0] = bqf; gp.C[0] = qb16; gp.bf16[0] = 1;
        gp.B[1] = wf_t + 1 * 64 * 512; gp.bias[1] = bkf; gp.C[1] = kb;   gp.bf16[1] = 1;
        gp.B[2] = wf_t + 2 * 64 * 512; gp.bias[2] = bvf; gp.C[2] = vb;   gp.bf16[2] = 1;
        gp.B[3] = wf_t + 3 * 64 * 512; gp.bias[3] = bsf; gp.C[3] = hf32; gp.bf16[3] = 0;
        mfma_flex<<<dim3(cdiv(N, 128), 4), 256, 0, stream>>>(hcur, gp, N, 512, 64);
    }
    aggf_kernel<<<cdiv(N, 4), 256, 0, stream>>>(qb16, kb, vb, offs, csrc, hf32, N);

    // --- mean pool + MLP ---
    pool_kernel<<<64, 256, 0, stream>>>(hf32, gbuf, N);
    mlp_kernel<<<1, 64, 0, stream>>>(gbuf, Wc1, bc1, Wc2, bc2, (float*)d_out);
}